// Round 15
// baseline (2209.760 us; speedup 1.0000x reference)
//
#include <hip/hip_runtime.h>
#include <hip/hip_bf16.h>

#define H 128
#define POLY 16
#define PPG 256          // pairs per graph
#define GNUM 1024
#define PTOT 262144
#define NTOT 16384
#define ETOT 131072
#define TTOT 1048576

#define NCHUNK 8
#define GPC (GNUM / NCHUNK)        // graphs per chunk = 128
#define ROWS (PTOT / NCHUNK)       // pair rows per chunk = 32768
#define NITER (3 * NCHUNK)         // 24 (layer,chunk) iterations

#define NB PTOT                    // one bucket per output pair row

#define XS 136                     // LDS row stride in shorts (b128 granule-even)

typedef __attribute__((ext_vector_type(8))) _Float16       f16x8;
typedef __attribute__((ext_vector_type(8))) unsigned short ushort8;
typedef __attribute__((ext_vector_type(4))) float          f32x4;

__device__ __forceinline__ unsigned short f2h(float f) {       // RNE f32 -> f16 bits
    _Float16 h = (_Float16)f;
    return __builtin_bit_cast(unsigned short, h);
}
__device__ __forceinline__ float h2f(unsigned short u) {
    _Float16 h = __builtin_bit_cast(_Float16, u);
    return (float)h;
}
// exact 2-way f16 split: x == hi + lo (f32 24-bit mantissa = 2x f16 12-bit halves)
__device__ __forceinline__ void split2(float x, unsigned short& h, unsigned short& l)
{
    h = f2h(x);
    l = f2h(x - h2f(h));
}
__device__ __forceinline__ f16x8 ldf16(const unsigned short* p)
{
    return __builtin_bit_cast(f16x8, *(const ushort8*)p);
}

// ---------------------------------------------------------------- init
__global__ __launch_bounds__(256)
void k_init_pair(const float* __restrict__ px, const float* __restrict__ Wp,
                 float* __restrict__ ph)
{
    const int tid = threadIdx.x;
    const int c4 = (tid & 31) * 4;
    float4 w[POLY];
#pragma unroll
    for (int k = 0; k < POLY; ++k) w[k] = *(const float4*)(Wp + k * H + c4);
    const size_t r0 = (size_t)blockIdx.x * 64 + (tid >> 5) * 8;
#pragma unroll
    for (int rr = 0; rr < 8; ++rr) {
        const size_t p = r0 + rr;
        const float4* xp = (const float4*)(px + p * POLY);
        const float4 v0 = xp[0], v1 = xp[1], v2 = xp[2], v3 = xp[3];
        const float x[POLY] = {v0.x, v0.y, v0.z, v0.w, v1.x, v1.y, v1.z, v1.w,
                               v2.x, v2.y, v2.z, v2.w, v3.x, v3.y, v3.z, v3.w};
        float4 a = make_float4(0.f, 0.f, 0.f, 0.f);
#pragma unroll
        for (int k = 0; k < POLY; ++k) {
            a.x = fmaf(x[k], w[k].x, a.x);
            a.y = fmaf(x[k], w[k].y, a.y);
            a.z = fmaf(x[k], w[k].z, a.z);
            a.w = fmaf(x[k], w[k].w, a.w);
        }
        *(float4*)(ph + p * H + c4) = a;
    }
}

__global__ __launch_bounds__(256)
void k_edge(const float* __restrict__ eh, const int* __restrict__ epos, float* ph)
{
    const int tid = threadIdx.x;
    const size_t e = (size_t)blockIdx.x * 2 + (tid >> 7);
    const int c = tid & 127;
    atomicAdd(&ph[(size_t)epos[e] * H + c], eh[e * H + c]);
}

__global__ __launch_bounds__(256)
void k_diag(const float* __restrict__ nh, const float* __restrict__ dx,
            const float* __restrict__ Wdg, const int* __restrict__ dpos, float* ph)
{
    const int tid = threadIdx.x;
    const int c4 = (tid & 31) * 4;
    float4 w[POLY];
#pragma unroll
    for (int k = 0; k < POLY; ++k) w[k] = *(const float4*)(Wdg + k * H + c4);
    const size_t n0 = (size_t)blockIdx.x * 64 + (tid >> 5) * 8;
#pragma unroll
    for (int rr = 0; rr < 8; ++rr) {
        const size_t n = n0 + rr;
        const float4* xp = (const float4*)(dx + n * POLY);
        const float4 v0 = xp[0], v1 = xp[1], v2 = xp[2], v3 = xp[3];
        const float x[POLY] = {v0.x, v0.y, v0.z, v0.w, v1.x, v1.y, v1.z, v1.w,
                               v2.x, v2.y, v2.z, v2.w, v3.x, v3.y, v3.z, v3.w};
        const float4 nv = *(const float4*)(nh + n * H + c4);
        float4 a = nv;
#pragma unroll
        for (int k = 0; k < POLY; ++k) {
            a.x = fmaf(x[k], w[k].x, a.x);
            a.y = fmaf(x[k], w[k].y, a.y);
            a.z = fmaf(x[k], w[k].z, a.z);
            a.w = fmaf(x[k], w[k].w, a.w);
        }
        float* dst = ph + (size_t)dpos[n] * H + c4;   // diag_pos unique
        const float4 old = *(const float4*)dst;
        a.x += old.x; a.y += old.y; a.z += old.z; a.w += old.w;
        *(float4*)dst = a;
    }
}

// ---------------------------------------------------------------- triple bucketing (by row)
__global__ __launch_bounds__(1024)
void k_zero(int* counts) { counts[blockIdx.x * 1024 + threadIdx.x] = 0; }

__global__ __launch_bounds__(256)
void k_count(const int* __restrict__ i0, int* counts)
{
    const int t = blockIdx.x * 256 + threadIdx.x;
    atomicAdd(&counts[i0[t]], 1);      // bucket = destination pair row; avg 4/bucket
}

// level-1 scan: 256 blocks x 1024 entries; local exclusive prefix -> offs, block sum -> bsum
__global__ __launch_bounds__(1024)
void k_scan1(const int* __restrict__ counts, int* __restrict__ offs, int* __restrict__ bsum)
{
    __shared__ int s[1024];
    const int t = threadIdx.x;
    const int i = blockIdx.x * 1024 + t;
    const int v = counts[i];
    s[t] = v;
    __syncthreads();
    for (int d = 1; d < 1024; d <<= 1) {
        int add = (t >= d) ? s[t - d] : 0;
        __syncthreads();
        s[t] += add;
        __syncthreads();
    }
    offs[i] = s[t] - v;
    if (t == 1023) bsum[blockIdx.x] = s[1023];
}

// level-2 scan: exclusive scan of the 256 block sums
__global__ __launch_bounds__(256)
void k_scan2(const int* __restrict__ bsum, int* __restrict__ bbase)
{
    __shared__ int s[256];
    const int t = threadIdx.x;
    const int v = bsum[t];
    s[t] = v;
    __syncthreads();
    for (int d = 1; d < 256; d <<= 1) {
        int add = (t >= d) ? s[t - d] : 0;
        __syncthreads();
        s[t] += add;
        __syncthreads();
    }
    bbase[t] = s[t] - v;
}

// level-3: add block bases; emit offs and cursor
__global__ __launch_bounds__(1024)
void k_scan3(int* __restrict__ offs, const int* __restrict__ bbase, int* __restrict__ cursor)
{
    const int i = blockIdx.x * 1024 + threadIdx.x;
    const int o = offs[i] + bbase[blockIdx.x];
    offs[i] = o;
    cursor[i] = o;
    if (i == 0) offs[NB] = TTOT;
}

__global__ __launch_bounds__(256)
void k_fill(const int* __restrict__ i0, const int* __restrict__ i1,
            const int* __restrict__ i2, int* cursor, unsigned short* __restrict__ tri16)
{
    const int t = blockIdx.x * 256 + threadIdx.x;
    const int a0 = i0[t];
    const int pos = atomicAdd(&cursor[a0], 1);
    tri16[pos] = (unsigned short)((i1[t] & 255) | ((i2[t] & 255) << 8));
}

// ---------------------------------------------------------------- MFMA MLP (2-way f16 split)
// stage 64x128 f32 tile -> 2 LDS f16 buffers (hi/lo), row stride XS shorts
__device__ __forceinline__ void stage2(const float* __restrict__ src,
                                       unsigned short* Xh, unsigned short* Xl, int tid)
{
#pragma unroll
    for (int it = 0; it < 4; ++it) {
        const int r = (tid >> 4) + it * 16;
        const int c = (tid & 15) * 8;
        const float4 v0 = *(const float4*)(src + (size_t)r * H + c);
        const float4 v1 = *(const float4*)(src + (size_t)r * H + c + 4);
        const float x[8] = {v0.x, v0.y, v0.z, v0.w, v1.x, v1.y, v1.z, v1.w};
        ushort8 vh, vl;
#pragma unroll
        for (int j = 0; j < 8; ++j) {
            unsigned short hh, ll;
            split2(x[j], hh, ll);
            vh[j] = hh; vl[j] = ll;
        }
        *(ushort8*)(Xh + r * XS + c) = vh;
        *(ushort8*)(Xl + r * XS + c) = vl;
    }
}

#define MFMA16F(A, B, C) __builtin_amdgcn_mfma_f32_16x16x32_f16(A, B, C, 0, 0, 0)

// one K=128 GEMM pass: acc += X @ W, 4-product 2-way f16 split (exact f32-level)
__device__ __forceinline__ void gemm2(const unsigned short* Xh, const unsigned short* Xl,
                                      const unsigned short* __restrict__ wp,
                                      const int rt, const int cb, const int lane,
                                      f32x4 (&acc)[2][4])
{
    const int arow = lane & 15, akb = (lane >> 4) * 8;
#pragma unroll
    for (int kc = 0; kc < 4; ++kc) {
        const int kin = kc * 32 + akb;
        f16x8 ah[2], al[2];
#pragma unroll
        for (int s = 0; s < 2; ++s) {
            const int ro = (rt + s * 16 + arow) * XS + kin;
            ah[s] = ldf16(Xh + ro);
            al[s] = ldf16(Xl + ro);
        }
#pragma unroll
        for (int j = 0; j < 4; ++j) {
            const unsigned short* bp = wp + (size_t)(kc * 8 + cb + j) * 1024 + lane * 8;
            const f16x8 bh = ldf16(bp);
            const f16x8 bl = ldf16(bp + 512);
#pragma unroll
            for (int s = 0; s < 2; ++s) {
                acc[s][j] = MFMA16F(ah[s], bh, acc[s][j]);
                acc[s][j] = MFMA16F(al[s], bh, acc[s][j]);
                acc[s][j] = MFMA16F(ah[s], bl, acc[s][j]);
                acc[s][j] = MFMA16F(al[s], bl, acc[s][j]);
            }
        }
    }
}

// m1/m2 body (grid-parity fused): bid parity selects weight set.
__device__ __forceinline__ void mlp_m12_body(int bid, const float* __restrict__ x1,
    const unsigned short* __restrict__ wa1, const float* __restrict__ ba1,
    const float* __restrict__ gg1, const float* __restrict__ bsh1,
    const unsigned short* __restrict__ wb1, const float* __restrict__ bb1,
    float* __restrict__ out1,
    const unsigned short* __restrict__ wa2, const float* __restrict__ ba2,
    const float* __restrict__ gg2, const float* __restrict__ bsh2,
    const unsigned short* __restrict__ wb2, const float* __restrict__ bb2,
    float* __restrict__ out2,
    unsigned short* Xh, unsigned short* Xl, int tid)
{
    const int lane = tid & 63, wid = tid >> 6;
    const int sel = bid & 1;
    const size_t row0 = (size_t)(bid >> 1) * 64;

    const unsigned short* wa = sel ? wa2 : wa1;
    const unsigned short* wb = sel ? wb2 : wb1;
    const float* ba  = sel ? ba2  : ba1;
    const float* gg  = sel ? gg2  : gg1;
    const float* bsh = sel ? bsh2 : bsh1;
    const float* bb  = sel ? bb2  : bb1;
    float* out = sel ? out2 : out1;

    const int rt = (wid >> 1) * 32;
    const int cb = (wid & 1) * 4;

    f32x4 acc[2][4];
#pragma unroll
    for (int s = 0; s < 2; ++s)
#pragma unroll
        for (int j = 0; j < 4; ++j)
#pragma unroll
            for (int q = 0; q < 4; ++q) acc[s][j][q] = 0.f;

    stage2(x1 + row0 * H, Xh, Xl, tid);
    __syncthreads();
    gemm2(Xh, Xl, wa, rt, cb, lane, acc);
    __syncthreads();

    const float inv_s = rsqrtf(1.0f + 1e-5f);
    const int crow = (lane >> 4) * 4, ccol = lane & 15;
#pragma unroll
    for (int j = 0; j < 4; ++j) {
        const int col = (cb + j) * 16 + ccol;
        const float g  = gg[col] * inv_s;
        const float a_ = ba[col];
        const float b_ = bsh[col];
#pragma unroll
        for (int s = 0; s < 2; ++s)
#pragma unroll
            for (int q = 0; q < 4; ++q) {
                float t = fmaf(acc[s][j][q] + a_, g, b_);
                t = fmaxf(t, 0.f);
                unsigned short hh, ll;
                split2(t, hh, ll);
                const int ro = (rt + s * 16 + crow + q) * XS + col;
                Xh[ro] = hh; Xl[ro] = ll;
                acc[s][j][q] = 0.f;
            }
    }
    __syncthreads();

    gemm2(Xh, Xl, wb, rt, cb, lane, acc);

#pragma unroll
    for (int j = 0; j < 4; ++j) {
        const int col = (cb + j) * 16 + ccol;
        const float bbv = bb[col];
#pragma unroll
        for (int s = 0; s < 2; ++s)
#pragma unroll
            for (int q = 0; q < 4; ++q) {
                const int row = rt + s * 16 + crow + q;
                out[(row0 + row) * H + col] = acc[s][j][q] + bbv;
            }
    }
}

// up body: GEMM1 over concat(x1, x2) K=256 via sequential staging; + x1 residual.
__device__ __forceinline__ void mlp_up_body(int bid, const float* __restrict__ x1,
    const float* __restrict__ x2,
    const unsigned short* __restrict__ wpa, const float* __restrict__ ba,
    const float* __restrict__ gg, const float* __restrict__ bsh,
    const unsigned short* __restrict__ wpb, const float* __restrict__ bb,
    float* __restrict__ out,
    unsigned short* Xh, unsigned short* Xl, int tid)
{
    const int lane = tid & 63, wid = tid >> 6;
    const size_t row0 = (size_t)bid * 64;
    const int rt = (wid >> 1) * 32;
    const int cb = (wid & 1) * 4;

    f32x4 acc[2][4];
#pragma unroll
    for (int s = 0; s < 2; ++s)
#pragma unroll
        for (int j = 0; j < 4; ++j)
#pragma unroll
            for (int q = 0; q < 4; ++q) acc[s][j][q] = 0.f;

    stage2(x1 + row0 * H, Xh, Xl, tid);
    __syncthreads();
    gemm2(Xh, Xl, wpa, rt, cb, lane, acc);
    __syncthreads();
    stage2(x2 + row0 * H, Xh, Xl, tid);
    __syncthreads();
    gemm2(Xh, Xl, wpa + 32 * 1024, rt, cb, lane, acc);
    __syncthreads();

    const float inv_s = rsqrtf(1.0f + 1e-5f);
    const int crow = (lane >> 4) * 4, ccol = lane & 15;
#pragma unroll
    for (int j = 0; j < 4; ++j) {
        const int col = (cb + j) * 16 + ccol;
        const float g  = gg[col] * inv_s;
        const float a_ = ba[col];
        const float b_ = bsh[col];
#pragma unroll
        for (int s = 0; s < 2; ++s)
#pragma unroll
            for (int q = 0; q < 4; ++q) {
                float t = fmaf(acc[s][j][q] + a_, g, b_);
                t = fmaxf(t, 0.f);
                unsigned short hh, ll;
                split2(t, hh, ll);
                const int ro = (rt + s * 16 + crow + q) * XS + col;
                Xh[ro] = hh; Xl[ro] = ll;
                acc[s][j][q] = 0.f;
            }
    }
    __syncthreads();

    gemm2(Xh, Xl, wpb, rt, cb, lane, acc);

#pragma unroll
    for (int j = 0; j < 4; ++j) {
        const int col = (cb + j) * 16 + ccol;
        const float bbv = bb[col];
#pragma unroll
        for (int s = 0; s < 2; ++s)
#pragma unroll
            for (int q = 0; q < 4; ++q) {
                const int row = rt + s * 16 + crow + q;
                float o = acc[s][j][q] + bbv + x1[(row0 + row) * H + col];
                out[(row0 + row) * H + col] = o;
            }
    }
}

// triple body (sorted, atomic-free): one wave per output row.
__device__ __forceinline__ void triple_body(int tb, const float* __restrict__ h1,
    const float* __restrict__ h2, const unsigned short* __restrict__ tri16,
    const int* __restrict__ offs, float* __restrict__ aggout, int tid)
{
    const int lane = tid & 63;
    const int lp   = tb * 4 + (tid >> 6);                   // local row in chunk
    const int start = offs[lp], end = offs[lp + 1];         // global tri16 positions
    const size_t base = (size_t)(lp >> 8) * PPG * H + lane * 2;
    float ax = 0.f, ay = 0.f;
    unsigned us = (start < end) ? tri16[start] : 0u;
    for (int t = start; t < end; ++t) {
        const unsigned usn = (t + 1 < end) ? tri16[t + 1] : 0u;   // prefetch next index
        const float2 a = *(const float2*)&h1[base + (size_t)(us & 255u) * H];
        const float2 b = *(const float2*)&h2[base + (size_t)(us >> 8) * H];
        ax = fmaf(a.x, b.x, ax);
        ay = fmaf(a.y, b.y, ay);
        us = usn;
    }
    float2 r;
    r.x = sqrtf(fmaxf(ax, 0.f) + 1e-12f) - sqrtf(fmaxf(-ax, 0.f) + 1e-12f);
    r.y = sqrtf(fmaxf(ay, 0.f) + 1e-12f) - sqrtf(fmaxf(-ay, 0.f) + 1e-12f);
    *(float2*)&aggout[(size_t)lp * H + lane * 2] = r;
}

__global__ __launch_bounds__(256)
void k_mlp_m12(const float* x1,
               const unsigned short* wa1, const float* ba1, const float* gg1,
               const float* bsh1, const unsigned short* wb1, const float* bb1, float* out1,
               const unsigned short* wa2, const float* ba2, const float* gg2,
               const float* bsh2, const unsigned short* wb2, const float* bb2, float* out2)
{
    __shared__ unsigned short Xh[64 * XS], Xl[64 * XS];   // 34 KiB
    mlp_m12_body(blockIdx.x, x1, wa1, ba1, gg1, bsh1, wb1, bb1, out1,
                 wa2, ba2, gg2, bsh2, wb2, bb2, out2, Xh, Xl, threadIdx.x);
}

// 3-stage pipeline dispatch: up(t-2) || triple(t-1) || m12(t), all independent.
// ilv=1: steady state (nm=1024,nu=512,nt=8192) -> 19-block groups of 2m+1u+16t
// ilv=0: sequential sections [m12 | up | triple] (edge dispatches).
__global__ __launch_bounds__(256)
void k_pipe(int nm, int nu, int nt, int ilv,
            // m12(t)
            const float* mx1,
            const unsigned short* mwa1, const float* mba1, const float* mgg1,
            const float* mbsh1, const unsigned short* mwb1, const float* mbb1, float* mout1,
            const unsigned short* mwa2, const float* mba2, const float* mgg2,
            const float* mbsh2, const unsigned short* mwb2, const float* mbb2, float* mout2,
            // up(t-2)
            const float* ux1, const float* ux2,
            const unsigned short* uwpa, const float* uba, const float* ugg,
            const float* ubsh, const unsigned short* uwpb, const float* ubb, float* uout,
            // triple(t-1)
            const float* th1, const float* th2, const unsigned short* tri16,
            const int* toffs, float* tagg)
{
    __shared__ unsigned short Xh[64 * XS], Xl[64 * XS];   // 34 KiB
    const int bid = blockIdx.x, tid = threadIdx.x;
    int type, id;
    if (ilv) {
        const int g = bid / 19, r = bid % 19;
        if (r < 2)       { type = 0; id = g * 2 + r; }
        else if (r == 2) { type = 1; id = g; }
        else             { type = 2; id = g * 16 + (r - 3); }
    } else {
        if (bid < nm)            { type = 0; id = bid; }
        else if (bid < nm + nu)  { type = 1; id = bid - nm; }
        else                     { type = 2; id = bid - nm - nu; }
    }
    if (type == 0)
        mlp_m12_body(id, mx1, mwa1, mba1, mgg1, mbsh1, mwb1, mbb1, mout1,
                     mwa2, mba2, mgg2, mbsh2, mwb2, mbb2, mout2, Xh, Xl, tid);
    else if (type == 1)
        mlp_up_body(id, ux1, ux2, uwpa, uba, ugg, ubsh, uwpb, ubb, uout, Xh, Xl, tid);
    else
        triple_body(id, th1, th2, tri16, toffs, tagg, tid);
}

// prepack W[K][128] f32 -> per-(kc,ct) B-fragment blocks: 64 lanes x 8 f16 x {hi,lo}
__global__ __launch_bounds__(64)
void k_prepack2(const float* __restrict__ W, int lstride,
                unsigned short* __restrict__ outp, int ostride)
{
    const int l = blockIdx.y;
    const float* w = W + (size_t)l * lstride;
    unsigned short* o = outp + (size_t)l * ostride + (size_t)blockIdx.x * 1024;
    const int lane = threadIdx.x;
    const int kbase = (blockIdx.x >> 3) * 32 + (lane >> 4) * 8;
    const int col   = (blockIdx.x & 7) * 16 + (lane & 15);
    ushort8 vh, vl;
#pragma unroll
    for (int j = 0; j < 8; ++j) {
        unsigned short hh, ll;
        split2(w[(size_t)(kbase + j) * H + col], hh, ll);
        vh[j] = hh; vl[j] = ll;
    }
    *(ushort8*)(o + lane * 8)       = vh;
    *(ushort8*)(o + 512 + lane * 8) = vl;
}

// ---------------------------------------------------------------- pooling + decode
__global__ __launch_bounds__(256)
void k_pool(const float* __restrict__ ph, const float* __restrict__ Wd,
            const float* __restrict__ bd, float* __restrict__ out)
{
    const int g = blockIdx.x;
    const int tid = threadIdx.x;
    const int c = tid & 127, half = tid >> 7;
    const size_t base = (size_t)g * PPG * H;
    float s = 0.f;
    for (int r = half * 128; r < half * 128 + 128; ++r)
        s += ph[base + (size_t)r * H + c];
    __shared__ float sother[128];
    __shared__ float red[128];
    if (half) sother[c] = s;
    __syncthreads();
    if (!half) {
        const float tot = s + sother[c];
        float d = 0.f;
#pragma unroll
        for (int i = 0; i < 16; ++i)
            d += ph[base + (size_t)(i * 17) * H + c];
        const float diag = d * (1.f / 16.f);
        const float offv = (tot - d) * (1.f / 240.f);
        red[c] = fmaf(diag, Wd[c], offv * Wd[128 + c]);
    }
    __syncthreads();
    if (tid < 64) {
        float r = red[tid] + red[tid + 64];
#pragma unroll
        for (int off = 32; off; off >>= 1) r += __shfl_down(r, off);
        if (tid == 0) out[g] = r + bd[0];
    }
}

// ---------------------------------------------------------------- launch
extern "C" void kernel_launch(void* const* d_in, const int* in_sizes, int n_in,
                              void* d_out, int out_size, void* d_ws, size_t ws_size,
                              hipStream_t stream)
{
    (void)in_sizes; (void)n_in; (void)out_size;
    // workspace layout (bytes)
    const size_t OFF_PH  = 0;                          // f32 [P*H]        134,217,728
    const size_t OFF_HA  = 134217728;                  // f32 [2][ROWS*H]   33,554,432
    const size_t OFF_HB  = 167772160;                  // f32 [2][ROWS*H]   33,554,432
    const size_t OFF_AGG = 201326592;                  // f32 [2][ROWS*H]   33,554,432
    const size_t OFF_TRI = 234881024;                  // u16 [T]            2,097,152
    const size_t OFF_INT = 236978176;                  // counts/offs/cursor/bsum ~3.2 MB
    const size_t OFF_WP  = 240128000;                  // packed weights     1,376,256
    const size_t NEED    = OFF_WP + 1376256;           // ~241.5 MB (proven OK r7-r14)
    if (ws_size < NEED) return;   // diagnostic guard: absmax=488 signature, no fault

    const float* pair_x = (const float*)d_in[0];
    const float* diag_x = (const float*)d_in[1];
    const float* node_h = (const float*)d_in[2];
    const float* edge_h = (const float*)d_in[3];
    const float* W_pair = (const float*)d_in[4];
    const float* W_diag = (const float*)d_in[5];
    const float* Wd     = (const float*)d_in[6];
    const float* bd     = (const float*)d_in[7];
    const float* mW[3][6];
    for (int p = 0; p < 3; ++p)
        for (int q = 0; q < 6; ++q)
            mW[p][q] = (const float*)d_in[8 + p * 6 + q];
    const int* edge_pos = (const int*)d_in[26];
    const int* diag_pos = (const int*)d_in[27];
    const int* tri_idx  = (const int*)d_in[28];

    char* w = (char*)d_ws;
    float*          ph   = (float*)(w + OFF_PH);
    float*          hA0  = (float*)(w + OFF_HA);
    float*          hB0  = (float*)(w + OFF_HB);
    float*          ag0  = (float*)(w + OFF_AGG);
    unsigned short* tri16 = (unsigned short*)(w + OFF_TRI);
    int*            counts = (int*)(w + OFF_INT);
    int*            offs   = counts + NB;              // NB+8 entries
    int*            cursor = offs + NB + 8;            // NB entries
    int*            bsum   = cursor + NB;              // 256
    int*            bbase  = bsum + 256;               // 256
    unsigned short* wp   = (unsigned short*)(w + OFF_WP);

    float* hA[2] = {hA0, hA0 + (size_t)ROWS * H};
    float* hB[2] = {hB0, hB0 + (size_t)ROWS * H};
    float* ag[2] = {ag0, ag0 + (size_t)ROWS * H};

    // packed-weight slots (shorts): block = 1024; m* = 32 blocks, upa = 64 blocks
    const int WPL = 229376;   // per-layer stride
    // slots: m1a 0, m1b 32768, m2a 65536, m2b 98304, upa 131072, upb 196608

    k_init_pair<<<PTOT / 64, 256, 0, stream>>>(pair_x, W_pair, ph);
    k_edge<<<ETOT / 2, 256, 0, stream>>>(edge_h, edge_pos, ph);
    k_diag<<<NTOT / 64, 256, 0, stream>>>(node_h, diag_x, W_diag, diag_pos, ph);

    k_prepack2<<<dim3(32, 3), 64, 0, stream>>>(mW[0][0], 16384, wp + 0,      WPL);
    k_prepack2<<<dim3(32, 3), 64, 0, stream>>>(mW[0][4], 16384, wp + 32768,  WPL);
    k_prepack2<<<dim3(32, 3), 64, 0, stream>>>(mW[1][0], 16384, wp + 65536,  WPL);
    k_prepack2<<<dim3(32, 3), 64, 0, stream>>>(mW[1][4], 16384, wp + 98304,  WPL);
    k_prepack2<<<dim3(64, 3), 64, 0, stream>>>(mW[2][0], 32768, wp + 131072, WPL);
    k_prepack2<<<dim3(32, 3), 64, 0, stream>>>(mW[2][4], 16384, wp + 196608, WPL);

    k_zero<<<NB / 1024, 1024, 0, stream>>>(counts);
    k_count<<<TTOT / 256, 256, 0, stream>>>(tri_idx, counts);
    k_scan1<<<NB / 1024, 1024, 0, stream>>>(counts, offs, bsum);
    k_scan2<<<1, 256, 0, stream>>>(bsum, bbase);
    k_scan3<<<NB / 1024, 1024, 0, stream>>>(offs, bbase, cursor);
    k_fill<<<TTOT / 256, 256, 0, stream>>>(tri_idx, tri_idx + TTOT, tri_idx + 2 * TTOT,
                                           cursor, tri16);

    const int NM = ROWS / 64 * 2;   // 1024
    const int NU = ROWS / 64;       // 512
    const int NT = ROWS / 4;        // 8192

    // D0: m12(0) standalone
    k_mlp_m12<<<NM, 256, 0, stream>>>(ph,
        wp + 0,     mW[0][1], mW[0][2], mW[0][3], wp + 32768, mW[0][5], hA[0],
        wp + 65536, mW[1][1], mW[1][2], mW[1][3], wp + 98304, mW[1][5], hB[0]);

    // D_i (i=1..25): up(i-2) || triple(i-1) || m12(i)
    for (int i = 1; i <= NITER + 1; ++i) {
        const int tm = i, tt = i - 1, tu = i - 2;
        const bool hasM = (tm < NITER);
        const bool hasT = (tt < NITER);
        const bool hasU = (tu >= 0);
        const int nm = hasM ? NM : 0, nu = hasU ? NU : 0, nt = hasT ? NT : 0;
        const int ilv = (hasM && hasU && hasT) ? 1 : 0;

        const int lm = hasM ? tm / NCHUNK : 0, cm = hasM ? tm % NCHUNK : 0;
        const int lu = hasU ? tu / NCHUNK : 0, cu = hasU ? tu % NCHUNK : 0;
        const int ct = hasT ? tt % NCHUNK : 0;

        const unsigned short* wm = wp + (size_t)lm * WPL;
        const unsigned short* wu = wp + (size_t)lu * WPL;
        const float* phm = ph + (size_t)cm * ROWS * H;
        float*       phu = ph + (size_t)cu * ROWS * H;

        k_pipe<<<nm + nu + nt, 256, 0, stream>>>(nm, nu, nt, ilv,
            // m12(tm) -> hA/hB[tm&1]
            phm,
            wm + 0,     mW[0][1] + lm * 128, mW[0][2] + lm * 128, mW[0][3] + lm * 128,
            wm + 32768, mW[0][5] + lm * 128, hA[tm & 1],
            wm + 65536, mW[1][1] + lm * 128, mW[1][2] + lm * 128, mW[1][3] + lm * 128,
            wm + 98304, mW[1][5] + lm * 128, hB[tm & 1],
            // up(tu): ph(cu) + ag[tu&1] -> ph(cu)
            phu, ag[tu >= 0 ? (tu & 1) : 0],
            wu + 131072, mW[2][1] + lu * 128, mW[2][2] + lu * 128, mW[2][3] + lu * 128,
            wu + 196608, mW[2][5] + lu * 128, phu,
            // triple(tt): hA/hB[tt&1] -> ag[tt&1]
            hA[tt >= 0 ? (tt & 1) : 0], hB[tt >= 0 ? (tt & 1) : 0], tri16,
            offs + (size_t)ct * ROWS, ag[tt >= 0 ? (tt & 1) : 0]);
    }
    k_pool<<<GNUM, 256, 0, stream>>>(ph, Wd, bd, (float*)d_out);
}

// Round 17
// 1738.420 us; speedup vs baseline: 1.2711x; 1.2711x over previous
//
#include <hip/hip_runtime.h>
#include <hip/hip_bf16.h>

#define H 128
#define POLY 16
#define PPG 256          // pairs per graph
#define GNUM 1024
#define PTOT 262144
#define NTOT 16384
#define ETOT 131072
#define TTOT 1048576

#define NCHUNK 4
#define GPC (GNUM / NCHUNK)        // graphs per chunk = 256
#define ROWS (PTOT / NCHUNK)       // pair rows per chunk = 65536

#define NB PTOT                    // one bucket per output pair row

#define XS 136                     // LDS row stride in shorts (b128 granule-even)

typedef __attribute__((ext_vector_type(8))) _Float16       f16x8;
typedef __attribute__((ext_vector_type(8))) unsigned short ushort8;
typedef __attribute__((ext_vector_type(4))) float          f32x4;

__device__ __forceinline__ unsigned short f2h(float f) {       // RNE f32 -> f16 bits
    _Float16 h = (_Float16)f;
    return __builtin_bit_cast(unsigned short, h);
}
__device__ __forceinline__ float h2f(unsigned short u) {
    _Float16 h = __builtin_bit_cast(_Float16, u);
    return (float)h;
}
// exact 2-way f16 split: x == hi + lo (f32 24-bit mantissa = 2x f16 12-bit halves)
__device__ __forceinline__ void split2(float x, unsigned short& h, unsigned short& l)
{
    h = f2h(x);
    l = f2h(x - h2f(h));
}
__device__ __forceinline__ f16x8 ldf16(const unsigned short* p)
{
    return __builtin_bit_cast(f16x8, *(const ushort8*)p);
}

// ---------------------------------------------------------------- prologue bodies
__device__ __forceinline__ void init_pair_body(int bid, const float* __restrict__ px,
                                               const float* __restrict__ Wp,
                                               float* __restrict__ ph, int tid)
{
    const int c4 = (tid & 31) * 4;
    float4 w[POLY];
#pragma unroll
    for (int k = 0; k < POLY; ++k) w[k] = *(const float4*)(Wp + k * H + c4);
    const size_t r0 = (size_t)bid * 64 + (tid >> 5) * 8;
#pragma unroll
    for (int rr = 0; rr < 8; ++rr) {
        const size_t p = r0 + rr;
        const float4* xp = (const float4*)(px + p * POLY);
        const float4 v0 = xp[0], v1 = xp[1], v2 = xp[2], v3 = xp[3];
        const float x[POLY] = {v0.x, v0.y, v0.z, v0.w, v1.x, v1.y, v1.z, v1.w,
                               v2.x, v2.y, v2.z, v2.w, v3.x, v3.y, v3.z, v3.w};
        float4 a = make_float4(0.f, 0.f, 0.f, 0.f);
#pragma unroll
        for (int k = 0; k < POLY; ++k) {
            a.x = fmaf(x[k], w[k].x, a.x);
            a.y = fmaf(x[k], w[k].y, a.y);
            a.z = fmaf(x[k], w[k].z, a.z);
            a.w = fmaf(x[k], w[k].w, a.w);
        }
        *(float4*)(ph + p * H + c4) = a;
    }
}

// prepack one fragment-block b of W[K][128] -> {hi,lo} f16 B-fragments
__device__ __forceinline__ void prepack_body(const float* __restrict__ W,
                                             unsigned short* __restrict__ o_base,
                                             int b, int lane)
{
    unsigned short* o = o_base + (size_t)b * 1024;
    const int kbase = (b >> 3) * 32 + (lane >> 4) * 8;
    const int col   = (b & 7) * 16 + (lane & 15);
    ushort8 vh, vl;
#pragma unroll
    for (int j = 0; j < 8; ++j) {
        unsigned short hh, ll;
        split2(W[(size_t)(kbase + j) * H + col], hh, ll);
        vh[j] = hh; vl[j] = ll;
    }
    *(ushort8*)(o + lane * 8)       = vh;
    *(ushort8*)(o + 512 + lane * 8) = vl;
}

#define WPL 229376   // packed weights per-layer stride (shorts)

// fused prologue: init_pair [0,4096) || count [4096,8192) || prepack [8192,8360)
__global__ __launch_bounds__(256)
void k_prologue(const float* __restrict__ px, const float* __restrict__ Wp,
                float* __restrict__ ph,
                const int* __restrict__ i0, int* __restrict__ counts,
                const float* __restrict__ Wm1a, const float* __restrict__ Wm1b,
                const float* __restrict__ Wm2a, const float* __restrict__ Wm2b,
                const float* __restrict__ Wupa, const float* __restrict__ Wupb,
                unsigned short* __restrict__ wp)
{
    const int bid = blockIdx.x, tid = threadIdx.x;
    if (bid < 4096) {
        init_pair_body(bid, px, Wp, ph, tid);
    } else if (bid < 8192) {
        const int t = (bid - 4096) * 256 + tid;
        atomicAdd(&counts[i0[t]], 1);
    } else {
        const int f = (bid - 8192) * 4 + (tid >> 6);   // fragment id in [0,672)
        const int lane = tid & 63;
        const int layer = f / 224, r = f % 224;
        unsigned short* wl = wp + (size_t)layer * WPL;
        if (r < 32)       prepack_body(Wm1a + (size_t)layer * 16384, wl + 0,      r,       lane);
        else if (r < 64)  prepack_body(Wm1b + (size_t)layer * 16384, wl + 32768,  r - 32,  lane);
        else if (r < 96)  prepack_body(Wm2a + (size_t)layer * 16384, wl + 65536,  r - 64,  lane);
        else if (r < 128) prepack_body(Wm2b + (size_t)layer * 16384, wl + 98304,  r - 96,  lane);
        else if (r < 192) prepack_body(Wupa + (size_t)layer * 32768, wl + 131072, r - 128, lane);
        else              prepack_body(Wupb + (size_t)layer * 16384, wl + 196608, r - 192, lane);
    }
}

// fused edge [0,65536) || diag [65536,65792) — both atomic, commutative
__global__ __launch_bounds__(256)
void k_edgediag(const float* __restrict__ eh, const int* __restrict__ epos,
                const float* __restrict__ nh, const float* __restrict__ dx,
                const float* __restrict__ Wdg, const int* __restrict__ dpos,
                float* ph)
{
    const int bid = blockIdx.x, tid = threadIdx.x;
    if (bid < ETOT / 2) {
        const size_t e = (size_t)bid * 2 + (tid >> 7);
        const int c = tid & 127;
        atomicAdd(&ph[(size_t)epos[e] * H + c], eh[e * H + c]);
    } else {
        const int db = bid - ETOT / 2;
        const int c4 = (tid & 31) * 4;
        float4 w[POLY];
#pragma unroll
        for (int k = 0; k < POLY; ++k) w[k] = *(const float4*)(Wdg + k * H + c4);
        const size_t n0 = (size_t)db * 64 + (tid >> 5) * 8;
#pragma unroll
        for (int rr = 0; rr < 8; ++rr) {
            const size_t n = n0 + rr;
            const float4* xp = (const float4*)(dx + n * POLY);
            const float4 v0 = xp[0], v1 = xp[1], v2 = xp[2], v3 = xp[3];
            const float x[POLY] = {v0.x, v0.y, v0.z, v0.w, v1.x, v1.y, v1.z, v1.w,
                                   v2.x, v2.y, v2.z, v2.w, v3.x, v3.y, v3.z, v3.w};
            const float4 nv = *(const float4*)(nh + n * H + c4);
            float4 a = nv;
#pragma unroll
            for (int k = 0; k < POLY; ++k) {
                a.x = fmaf(x[k], w[k].x, a.x);
                a.y = fmaf(x[k], w[k].y, a.y);
                a.z = fmaf(x[k], w[k].z, a.z);
                a.w = fmaf(x[k], w[k].w, a.w);
            }
            float* dst = ph + (size_t)dpos[n] * H + c4;
            atomicAdd(dst + 0, a.x);
            atomicAdd(dst + 1, a.y);
            atomicAdd(dst + 2, a.z);
            atomicAdd(dst + 3, a.w);
        }
    }
}

// ---------------------------------------------------------------- triple bucketing (by row)
__global__ __launch_bounds__(1024)
void k_zero(int* counts) { counts[blockIdx.x * 1024 + threadIdx.x] = 0; }

// level-1 scan: 256 blocks x 1024 entries; local exclusive prefix -> offs, block sum -> bsum
__global__ __launch_bounds__(1024)
void k_scan1(const int* __restrict__ counts, int* __restrict__ offs, int* __restrict__ bsum)
{
    __shared__ int s[1024];
    const int t = threadIdx.x;
    const int i = blockIdx.x * 1024 + t;
    const int v = counts[i];
    s[t] = v;
    __syncthreads();
    for (int d = 1; d < 1024; d <<= 1) {
        int add = (t >= d) ? s[t - d] : 0;
        __syncthreads();
        s[t] += add;
        __syncthreads();
    }
    offs[i] = s[t] - v;
    if (t == 1023) bsum[blockIdx.x] = s[1023];
}

// level-2 scan: exclusive scan of the 256 block sums
__global__ __launch_bounds__(256)
void k_scan2(const int* __restrict__ bsum, int* __restrict__ bbase)
{
    __shared__ int s[256];
    const int t = threadIdx.x;
    const int v = bsum[t];
    s[t] = v;
    __syncthreads();
    for (int d = 1; d < 256; d <<= 1) {
        int add = (t >= d) ? s[t - d] : 0;
        __syncthreads();
        s[t] += add;
        __syncthreads();
    }
    bbase[t] = s[t] - v;
}

// level-3: add block bases; emit offs and cursor
__global__ __launch_bounds__(1024)
void k_scan3(int* __restrict__ offs, const int* __restrict__ bbase, int* __restrict__ cursor)
{
    const int i = blockIdx.x * 1024 + threadIdx.x;
    const int o = offs[i] + bbase[blockIdx.x];
    offs[i] = o;
    cursor[i] = o;
    if (i == 0) offs[NB] = TTOT;
}

// ---------------------------------------------------------------- MFMA MLP (2-way f16 split)
// stage 64x128 f32 tile -> 2 LDS f16 buffers (hi/lo), row stride XS shorts
__device__ __forceinline__ void stage2(const float* __restrict__ src,
                                       unsigned short* Xh, unsigned short* Xl, int tid)
{
#pragma unroll
    for (int it = 0; it < 4; ++it) {
        const int r = (tid >> 4) + it * 16;
        const int c = (tid & 15) * 8;
        const float4 v0 = *(const float4*)(src + (size_t)r * H + c);
        const float4 v1 = *(const float4*)(src + (size_t)r * H + c + 4);
        const float x[8] = {v0.x, v0.y, v0.z, v0.w, v1.x, v1.y, v1.z, v1.w};
        ushort8 vh, vl;
#pragma unroll
        for (int j = 0; j < 8; ++j) {
            unsigned short hh, ll;
            split2(x[j], hh, ll);
            vh[j] = hh; vl[j] = ll;
        }
        *(ushort8*)(Xh + r * XS + c) = vh;
        *(ushort8*)(Xl + r * XS + c) = vl;
    }
}

#define MFMA16F(A, B, C) __builtin_amdgcn_mfma_f32_16x16x32_f16(A, B, C, 0, 0, 0)

// one K=128 GEMM pass: acc += X @ W, 4-product 2-way f16 split (exact f32-level)
__device__ __forceinline__ void gemm2(const unsigned short* Xh, const unsigned short* Xl,
                                      const unsigned short* __restrict__ wp,
                                      const int rt, const int cb, const int lane,
                                      f32x4 (&acc)[2][4])
{
    const int arow = lane & 15, akb = (lane >> 4) * 8;
#pragma unroll
    for (int kc = 0; kc < 4; ++kc) {
        const int kin = kc * 32 + akb;
        f16x8 ah[2], al[2];
#pragma unroll
        for (int s = 0; s < 2; ++s) {
            const int ro = (rt + s * 16 + arow) * XS + kin;
            ah[s] = ldf16(Xh + ro);
            al[s] = ldf16(Xl + ro);
        }
#pragma unroll
        for (int j = 0; j < 4; ++j) {
            const unsigned short* bp = wp + (size_t)(kc * 8 + cb + j) * 1024 + lane * 8;
            const f16x8 bh = ldf16(bp);
            const f16x8 bl = ldf16(bp + 512);
#pragma unroll
            for (int s = 0; s < 2; ++s) {
                acc[s][j] = MFMA16F(ah[s], bh, acc[s][j]);
                acc[s][j] = MFMA16F(al[s], bh, acc[s][j]);
                acc[s][j] = MFMA16F(ah[s], bl, acc[s][j]);
                acc[s][j] = MFMA16F(al[s], bl, acc[s][j]);
            }
        }
    }
}

// m1/m2 body (grid-parity fused): bid parity selects weight set.
__device__ __forceinline__ void mlp_m12_body(int bid, const float* __restrict__ x1,
    const unsigned short* __restrict__ wa1, const float* __restrict__ ba1,
    const float* __restrict__ gg1, const float* __restrict__ bsh1,
    const unsigned short* __restrict__ wb1, const float* __restrict__ bb1,
    float* __restrict__ out1,
    const unsigned short* __restrict__ wa2, const float* __restrict__ ba2,
    const float* __restrict__ gg2, const float* __restrict__ bsh2,
    const unsigned short* __restrict__ wb2, const float* __restrict__ bb2,
    float* __restrict__ out2,
    unsigned short* Xh, unsigned short* Xl, int tid)
{
    const int lane = tid & 63, wid = tid >> 6;
    const int sel = bid & 1;
    const size_t row0 = (size_t)(bid >> 1) * 64;

    const unsigned short* wa = sel ? wa2 : wa1;
    const unsigned short* wb = sel ? wb2 : wb1;
    const float* ba  = sel ? ba2  : ba1;
    const float* gg  = sel ? gg2  : gg1;
    const float* bsh = sel ? bsh2 : bsh1;
    const float* bb  = sel ? bb2  : bb1;
    float* out = sel ? out2 : out1;

    const int rt = (wid >> 1) * 32;
    const int cb = (wid & 1) * 4;

    f32x4 acc[2][4];
#pragma unroll
    for (int s = 0; s < 2; ++s)
#pragma unroll
        for (int j = 0; j < 4; ++j)
#pragma unroll
            for (int q = 0; q < 4; ++q) acc[s][j][q] = 0.f;

    stage2(x1 + row0 * H, Xh, Xl, tid);
    __syncthreads();
    gemm2(Xh, Xl, wa, rt, cb, lane, acc);
    __syncthreads();

    const float inv_s = rsqrtf(1.0f + 1e-5f);
    const int crow = (lane >> 4) * 4, ccol = lane & 15;
#pragma unroll
    for (int j = 0; j < 4; ++j) {
        const int col = (cb + j) * 16 + ccol;
        const float g  = gg[col] * inv_s;
        const float a_ = ba[col];
        const float b_ = bsh[col];
#pragma unroll
        for (int s = 0; s < 2; ++s)
#pragma unroll
            for (int q = 0; q < 4; ++q) {
                float t = fmaf(acc[s][j][q] + a_, g, b_);
                t = fmaxf(t, 0.f);
                unsigned short hh, ll;
                split2(t, hh, ll);
                const int ro = (rt + s * 16 + crow + q) * XS + col;
                Xh[ro] = hh; Xl[ro] = ll;
                acc[s][j][q] = 0.f;
            }
    }
    __syncthreads();

    gemm2(Xh, Xl, wb, rt, cb, lane, acc);

#pragma unroll
    for (int j = 0; j < 4; ++j) {
        const int col = (cb + j) * 16 + ccol;
        const float bbv = bb[col];
#pragma unroll
        for (int s = 0; s < 2; ++s)
#pragma unroll
            for (int q = 0; q < 4; ++q) {
                const int row = rt + s * 16 + crow + q;
                out[(row0 + row) * H + col] = acc[s][j][q] + bbv;
            }
    }
}

// up body: GEMM1 over concat(x1, x2) K=256 via sequential staging; + x1 residual.
__device__ __forceinline__ void mlp_up_body(int bid, const float* __restrict__ x1,
    const float* __restrict__ x2,
    const unsigned short* __restrict__ wpa, const float* __restrict__ ba,
    const float* __restrict__ gg, const float* __restrict__ bsh,
    const unsigned short* __restrict__ wpb, const float* __restrict__ bb,
    float* __restrict__ out,
    unsigned short* Xh, unsigned short* Xl, int tid)
{
    const int lane = tid & 63, wid = tid >> 6;
    const size_t row0 = (size_t)bid * 64;
    const int rt = (wid >> 1) * 32;
    const int cb = (wid & 1) * 4;

    f32x4 acc[2][4];
#pragma unroll
    for (int s = 0; s < 2; ++s)
#pragma unroll
        for (int j = 0; j < 4; ++j)
#pragma unroll
            for (int q = 0; q < 4; ++q) acc[s][j][q] = 0.f;

    stage2(x1 + row0 * H, Xh, Xl, tid);
    __syncthreads();
    gemm2(Xh, Xl, wpa, rt, cb, lane, acc);
    __syncthreads();
    stage2(x2 + row0 * H, Xh, Xl, tid);
    __syncthreads();
    gemm2(Xh, Xl, wpa + 32 * 1024, rt, cb, lane, acc);
    __syncthreads();

    const float inv_s = rsqrtf(1.0f + 1e-5f);
    const int crow = (lane >> 4) * 4, ccol = lane & 15;
#pragma unroll
    for (int j = 0; j < 4; ++j) {
        const int col = (cb + j) * 16 + ccol;
        const float g  = gg[col] * inv_s;
        const float a_ = ba[col];
        const float b_ = bsh[col];
#pragma unroll
        for (int s = 0; s < 2; ++s)
#pragma unroll
            for (int q = 0; q < 4; ++q) {
                float t = fmaf(acc[s][j][q] + a_, g, b_);
                t = fmaxf(t, 0.f);
                unsigned short hh, ll;
                split2(t, hh, ll);
                const int ro = (rt + s * 16 + crow + q) * XS + col;
                Xh[ro] = hh; Xl[ro] = ll;
                acc[s][j][q] = 0.f;
            }
    }
    __syncthreads();

    gemm2(Xh, Xl, wpb, rt, cb, lane, acc);

#pragma unroll
    for (int j = 0; j < 4; ++j) {
        const int col = (cb + j) * 16 + ccol;
        const float bbv = bb[col];
#pragma unroll
        for (int s = 0; s < 2; ++s)
#pragma unroll
            for (int q = 0; q < 4; ++q) {
                const int row = rt + s * 16 + crow + q;
                float o = acc[s][j][q] + bbv + x1[(row0 + row) * H + col];
                out[(row0 + row) * H + col] = o;
            }
    }
}

// first dispatch of the loop: m12(layer0,chunk0) [0,2048) || k_fill [2048,6144)
__global__ __launch_bounds__(256)
void k_m12fill(const float* x1,
               const unsigned short* wa1, const float* ba1, const float* gg1,
               const float* bsh1, const unsigned short* wb1, const float* bb1, float* out1,
               const unsigned short* wa2, const float* ba2, const float* gg2,
               const float* bsh2, const unsigned short* wb2, const float* bb2, float* out2,
               const int* __restrict__ i0, const int* __restrict__ i1,
               const int* __restrict__ i2, int* cursor,
               unsigned short* __restrict__ tri16)
{
    __shared__ unsigned short Xh[64 * XS], Xl[64 * XS];   // 34 KiB
    const int bid = blockIdx.x, tid = threadIdx.x;
    if (bid < ROWS / 64 * 2) {
        mlp_m12_body(bid, x1, wa1, ba1, gg1, bsh1, wb1, bb1, out1,
                     wa2, ba2, gg2, bsh2, wb2, bb2, out2, Xh, Xl, tid);
    } else {
        const int t = (bid - ROWS / 64 * 2) * 256 + tid;
        const int a0 = i0[t];
        const int pos = atomicAdd(&cursor[a0], 1);
        tri16[pos] = (unsigned short)((i1[t] & 255) | ((i2[t] & 255) << 8));
    }
}

__global__ __launch_bounds__(256)
void k_mlp_up(const float* x1, const float* x2,
              const unsigned short* wpa, const float* ba, const float* gg,
              const float* bsh, const unsigned short* wpb, const float* bb, float* out)
{
    __shared__ unsigned short Xh[64 * XS], Xl[64 * XS];   // 34 KiB
    mlp_up_body(blockIdx.x, x1, x2, wpa, ba, gg, bsh, wpb, bb, out,
                Xh, Xl, threadIdx.x);
}

// heterogeneous dispatch: blocks [0,1024) run up(chunk cu); blocks [1024,3072)
// run m12 of an INDEPENDENT chunk (next chunk / next layer). up blocks first —
// they are a single wave-of-blocks; m12 fills CUs behind them.
__global__ __launch_bounds__(256)
void k_fused(const float* ux1, const float* ux2,
             const unsigned short* uwpa, const float* uba, const float* ugg,
             const float* ubsh, const unsigned short* uwpb, const float* ubb, float* uout,
             const float* mx1,
             const unsigned short* mwa1, const float* mba1, const float* mgg1,
             const float* mbsh1, const unsigned short* mwb1, const float* mbb1, float* mout1,
             const unsigned short* mwa2, const float* mba2, const float* mgg2,
             const float* mbsh2, const unsigned short* mwb2, const float* mbb2, float* mout2)
{
    __shared__ unsigned short Xh[64 * XS], Xl[64 * XS];   // 34 KiB
    const int bid = blockIdx.x;
    if (bid < ROWS / 64) {
        mlp_up_body(bid, ux1, ux2, uwpa, uba, ugg, ubsh, uwpb, ubb, uout,
                    Xh, Xl, threadIdx.x);
    } else {
        mlp_m12_body(bid - ROWS / 64, mx1, mwa1, mba1, mgg1, mbsh1, mwb1, mbb1, mout1,
                     mwa2, mba2, mgg2, mbsh2, mwb2, mbb2, mout2, Xh, Xl, threadIdx.x);
    }
}

// ---------------------------------------------------------------- triple (sorted, atomic-free)
__global__ __launch_bounds__(256)
void k_triple_s(const float* __restrict__ h1, const float* __restrict__ h2,
                const unsigned short* __restrict__ tri16,
                const int* __restrict__ offs,      // pre-offset by chunk row base
                float* __restrict__ aggout)
{
    const int lane = threadIdx.x & 63;
    const int lp   = blockIdx.x * 4 + (threadIdx.x >> 6);   // local row in chunk
    const int start = offs[lp], end = offs[lp + 1];         // global tri16 positions
    const size_t base = (size_t)(lp >> 8) * PPG * H + lane * 2;
    float ax = 0.f, ay = 0.f;
    unsigned us = (start < end) ? tri16[start] : 0u;
    for (int t = start; t < end; ++t) {
        const unsigned usn = (t + 1 < end) ? tri16[t + 1] : 0u;   // prefetch next index
        const float2 a = *(const float2*)&h1[base + (size_t)(us & 255u) * H];
        const float2 b = *(const float2*)&h2[base + (size_t)(us >> 8) * H];
        ax = fmaf(a.x, b.x, ax);
        ay = fmaf(a.y, b.y, ay);
        us = usn;
    }
    float2 r;
    r.x = sqrtf(fmaxf(ax, 0.f) + 1e-12f) - sqrtf(fmaxf(-ax, 0.f) + 1e-12f);
    r.y = sqrtf(fmaxf(ay, 0.f) + 1e-12f) - sqrtf(fmaxf(-ay, 0.f) + 1e-12f);
    *(float2*)&aggout[(size_t)lp * H + lane * 2] = r;
}

// ---------------------------------------------------------------- pooling + decode
__global__ __launch_bounds__(256)
void k_pool(const float* __restrict__ ph, const float* __restrict__ Wd,
            const float* __restrict__ bd, float* __restrict__ out)
{
    const int g = blockIdx.x;
    const int tid = threadIdx.x;
    const int c = tid & 127, half = tid >> 7;
    const size_t base = (size_t)g * PPG * H;
    float s = 0.f;
    for (int r = half * 128; r < half * 128 + 128; ++r)
        s += ph[base + (size_t)r * H + c];
    __shared__ float sother[128];
    __shared__ float red[128];
    if (half) sother[c] = s;
    __syncthreads();
    if (!half) {
        const float tot = s + sother[c];
        float d = 0.f;
#pragma unroll
        for (int i = 0; i < 16; ++i)
            d += ph[base + (size_t)(i * 17) * H + c];
        const float diag = d * (1.f / 16.f);
        const float offv = (tot - d) * (1.f / 240.f);
        red[c] = fmaf(diag, Wd[c], offv * Wd[128 + c]);
    }
    __syncthreads();
    if (tid < 64) {
        float r = red[tid] + red[tid + 64];
#pragma unroll
        for (int off = 32; off; off >>= 1) r += __shfl_down(r, off);
        if (tid == 0) out[g] = r + bd[0];
    }
}

// ---------------------------------------------------------------- launch
extern "C" void kernel_launch(void* const* d_in, const int* in_sizes, int n_in,
                              void* d_out, int out_size, void* d_ws, size_t ws_size,
                              hipStream_t stream)
{
    (void)in_sizes; (void)n_in; (void)out_size;
    // workspace layout (bytes)
    const size_t OFF_PH  = 0;                          // f32 [P*H]      134,217,728
    const size_t OFF_HA  = 134217728;                  // f32 [ROWS*H]    33,554,432
    const size_t OFF_HB  = 167772160;                  // f32 [ROWS*H]    33,554,432
    const size_t OFF_AGG = 201326592;                  // f32 [ROWS*H]    33,554,432
    const size_t OFF_TRI = 234881024;                  // u16 [T]          2,097,152
    const size_t OFF_INT = 236978176;                  // counts/offs/cursor/bsum ~3.2 MB
    const size_t OFF_WP  = 240128000;                  // packed weights   1,376,256
    const size_t NEED    = OFF_WP + 1376256;           // ~241.5 MB (proven OK r7-r15)
    if (ws_size < NEED) return;   // diagnostic guard: absmax=488 signature, no fault

    const float* pair_x = (const float*)d_in[0];
    const float* diag_x = (const float*)d_in[1];
    const float* node_h = (const float*)d_in[2];
    const float* edge_h = (const float*)d_in[3];
    const float* W_pair = (const float*)d_in[4];
    const float* W_diag = (const float*)d_in[5];
    const float* Wd     = (const float*)d_in[6];
    const float* bd     = (const float*)d_in[7];
    const float* mW[3][6];
    for (int p = 0; p < 3; ++p)
        for (int q = 0; q < 6; ++q)
            mW[p][q] = (const float*)d_in[8 + p * 6 + q];
    const int* edge_pos = (const int*)d_in[26];
    const int* diag_pos = (const int*)d_in[27];
    const int* tri_idx  = (const int*)d_in[28];

    char* w = (char*)d_ws;
    float*          ph   = (float*)(w + OFF_PH);
    float*          hA   = (float*)(w + OFF_HA);
    float*          hB   = (float*)(w + OFF_HB);
    float*          aggC = (float*)(w + OFF_AGG);
    unsigned short* tri16 = (unsigned short*)(w + OFF_TRI);
    int*            counts = (int*)(w + OFF_INT);
    int*            offs   = counts + NB;              // NB+8 entries
    int*            cursor = offs + NB + 8;            // NB entries
    int*            bsum   = cursor + NB;              // 256
    int*            bbase  = bsum + 256;               // 256
    unsigned short* wp   = (unsigned short*)(w + OFF_WP);

    // slots (shorts): m1a 0, m1b 32768, m2a 65536, m2b 98304, upa 131072, upb 196608

    k_zero<<<NB / 1024, 1024, 0, stream>>>(counts);
    // init_pair || count || prepack (all independent)
    k_prologue<<<4096 + 4096 + 168, 256, 0, stream>>>(pair_x, W_pair, ph,
        tri_idx, counts,
        mW[0][0], mW[0][4], mW[1][0], mW[1][4], mW[2][0], mW[2][4], wp);
    // edge || diag (atomic, commutative; both after init_pair)
    k_edgediag<<<ETOT / 2 + NTOT / 64, 256, 0, stream>>>(edge_h, edge_pos,
        node_h, diag_x, W_diag, diag_pos, ph);

    k_scan1<<<NB / 1024, 1024, 0, stream>>>(counts, offs, bsum);
    k_scan2<<<1, 256, 0, stream>>>(bsum, bbase);
    k_scan3<<<NB / 1024, 1024, 0, stream>>>(offs, bbase, cursor);

    // first m12 || fill (fill = TTOT/256 = 4096 blocks; hides under 2048 MFMA blocks)
    k_m12fill<<<ROWS / 64 * 2 + TTOT / 256, 256, 0, stream>>>(ph,
        wp + 0,     mW[0][1], mW[0][2], mW[0][3], wp + 32768, mW[0][5], hA,
        wp + 65536, mW[1][1], mW[1][2], mW[1][3], wp + 98304, mW[1][5], hB,
        tri_idx, tri_idx + TTOT, tri_idx + 2 * TTOT, cursor, tri16);

    for (int l = 0; l < 3; ++l) {
        const unsigned short* wl = wp + (size_t)l * WPL;
        for (int c = 0; c < NCHUNK; ++c) {
            float* phc = ph + (size_t)c * ROWS * H;
            k_triple_s<<<ROWS / 4, 256, 0, stream>>>(hA, hB, tri16,
                                                     offs + (size_t)c * ROWS, aggC);
            const bool has_next = (c < NCHUNK - 1) || (l < 2);
            if (has_next) {
                const int nl = (c < NCHUNK - 1) ? l : l + 1;
                const int nc = (c < NCHUNK - 1) ? c + 1 : 0;
                const unsigned short* wn = wp + (size_t)nl * WPL;
                float* phn = ph + (size_t)nc * ROWS * H;
                k_fused<<<ROWS / 64 * 3, 256, 0, stream>>>(
                    // up(l, c)
                    phc, aggC,
                    wl + 131072, mW[2][1] + l * 128, mW[2][2] + l * 128,
                    mW[2][3] + l * 128, wl + 196608, mW[2][5] + l * 128, phc,
                    // m12(nl, nc)
                    phn,
                    wn + 0,      mW[0][1] + nl * 128, mW[0][2] + nl * 128,
                    mW[0][3] + nl * 128, wn + 32768,  mW[0][5] + nl * 128, hA,
                    wn + 65536,  mW[1][1] + nl * 128, mW[1][2] + nl * 128,
                    mW[1][3] + nl * 128, wn + 98304,  mW[1][5] + nl * 128, hB);
            } else {
                k_mlp_up<<<ROWS / 64, 256, 0, stream>>>(phc, aggC,
                    wl + 131072, mW[2][1] + l * 128, mW[2][2] + l * 128,
                    mW[2][3] + l * 128, wl + 196608, mW[2][5] + l * 128, phc);
            }
        }
    }
    k_pool<<<GNUM, 256, 0, stream>>>(ph, Wd, bd, (float*)d_out);
}

// Round 18
// 1700.287 us; speedup vs baseline: 1.2996x; 1.0224x over previous
//
#include <hip/hip_runtime.h>
#include <hip/hip_bf16.h>

#define H 128
#define POLY 16
#define PPG 256          // pairs per graph
#define GNUM 1024
#define PTOT 262144
#define NTOT 16384
#define ETOT 131072
#define TTOT 1048576

#define NCHUNK 4
#define GPC (GNUM / NCHUNK)        // graphs per chunk = 256
#define ROWS (PTOT / NCHUNK)       // pair rows per chunk = 65536

#define NB PTOT                    // one bucket per output pair row

#define XS 136                     // LDS row stride in shorts (b128 granule-even)

typedef __attribute__((ext_vector_type(8))) _Float16       f16x8;
typedef __attribute__((ext_vector_type(8))) unsigned short ushort8;
typedef __attribute__((ext_vector_type(4))) float          f32x4;

__device__ __forceinline__ unsigned short f2h(float f) {       // RNE f32 -> f16 bits
    _Float16 h = (_Float16)f;
    return __builtin_bit_cast(unsigned short, h);
}
__device__ __forceinline__ float h2f(unsigned short u) {
    _Float16 h = __builtin_bit_cast(_Float16, u);
    return (float)h;
}
// exact 2-way f16 split: x == hi + lo (f32 24-bit mantissa = 2x f16 12-bit halves)
__device__ __forceinline__ void split2(float x, unsigned short& h, unsigned short& l)
{
    h = f2h(x);
    l = f2h(x - h2f(h));
}
__device__ __forceinline__ f16x8 ldf16(const unsigned short* p)
{
    return __builtin_bit_cast(f16x8, *(const ushort8*)p);
}

// ---------------------------------------------------------------- init
__global__ __launch_bounds__(256)
void k_init_pair(const float* __restrict__ px, const float* __restrict__ Wp,
                 float* __restrict__ ph)
{
    const int tid = threadIdx.x;
    const int c4 = (tid & 31) * 4;
    float4 w[POLY];
#pragma unroll
    for (int k = 0; k < POLY; ++k) w[k] = *(const float4*)(Wp + k * H + c4);
    const size_t r0 = (size_t)blockIdx.x * 64 + (tid >> 5) * 8;
#pragma unroll
    for (int rr = 0; rr < 8; ++rr) {
        const size_t p = r0 + rr;
        const float4* xp = (const float4*)(px + p * POLY);
        const float4 v0 = xp[0], v1 = xp[1], v2 = xp[2], v3 = xp[3];
        const float x[POLY] = {v0.x, v0.y, v0.z, v0.w, v1.x, v1.y, v1.z, v1.w,
                               v2.x, v2.y, v2.z, v2.w, v3.x, v3.y, v3.z, v3.w};
        float4 a = make_float4(0.f, 0.f, 0.f, 0.f);
#pragma unroll
        for (int k = 0; k < POLY; ++k) {
            a.x = fmaf(x[k], w[k].x, a.x);
            a.y = fmaf(x[k], w[k].y, a.y);
            a.z = fmaf(x[k], w[k].z, a.z);
            a.w = fmaf(x[k], w[k].w, a.w);
        }
        *(float4*)(ph + p * H + c4) = a;
    }
}

__global__ __launch_bounds__(256)
void k_edge(const float* __restrict__ eh, const int* __restrict__ epos, float* ph)
{
    const int tid = threadIdx.x;
    const size_t e = (size_t)blockIdx.x * 2 + (tid >> 7);
    const int c = tid & 127;
    atomicAdd(&ph[(size_t)epos[e] * H + c], eh[e * H + c]);
}

__global__ __launch_bounds__(256)
void k_diag(const float* __restrict__ nh, const float* __restrict__ dx,
            const float* __restrict__ Wdg, const int* __restrict__ dpos, float* ph)
{
    const int tid = threadIdx.x;
    const int c4 = (tid & 31) * 4;
    float4 w[POLY];
#pragma unroll
    for (int k = 0; k < POLY; ++k) w[k] = *(const float4*)(Wdg + k * H + c4);
    const size_t n0 = (size_t)blockIdx.x * 64 + (tid >> 5) * 8;
#pragma unroll
    for (int rr = 0; rr < 8; ++rr) {
        const size_t n = n0 + rr;
        const float4* xp = (const float4*)(dx + n * POLY);
        const float4 v0 = xp[0], v1 = xp[1], v2 = xp[2], v3 = xp[3];
        const float x[POLY] = {v0.x, v0.y, v0.z, v0.w, v1.x, v1.y, v1.z, v1.w,
                               v2.x, v2.y, v2.z, v2.w, v3.x, v3.y, v3.z, v3.w};
        const float4 nv = *(const float4*)(nh + n * H + c4);
        float4 a = nv;
#pragma unroll
        for (int k = 0; k < POLY; ++k) {
            a.x = fmaf(x[k], w[k].x, a.x);
            a.y = fmaf(x[k], w[k].y, a.y);
            a.z = fmaf(x[k], w[k].z, a.z);
            a.w = fmaf(x[k], w[k].w, a.w);
        }
        float* dst = ph + (size_t)dpos[n] * H + c4;   // diag_pos unique
        const float4 old = *(const float4*)dst;
        a.x += old.x; a.y += old.y; a.z += old.z; a.w += old.w;
        *(float4*)dst = a;
    }
}

// ---------------------------------------------------------------- triple bucketing (by row)
__global__ __launch_bounds__(1024)
void k_zero(int* counts) { counts[blockIdx.x * 1024 + threadIdx.x] = 0; }

__global__ __launch_bounds__(256)
void k_count(const int* __restrict__ i0, int* counts)
{
    const int t = blockIdx.x * 256 + threadIdx.x;
    atomicAdd(&counts[i0[t]], 1);      // bucket = destination pair row; avg 4/bucket
}

// level-1 scan: 256 blocks x 1024 entries; local exclusive prefix -> offs, block sum -> bsum
__global__ __launch_bounds__(1024)
void k_scan1(const int* __restrict__ counts, int* __restrict__ offs, int* __restrict__ bsum)
{
    __shared__ int s[1024];
    const int t = threadIdx.x;
    const int i = blockIdx.x * 1024 + t;
    const int v = counts[i];
    s[t] = v;
    __syncthreads();
    for (int d = 1; d < 1024; d <<= 1) {
        int add = (t >= d) ? s[t - d] : 0;
        __syncthreads();
        s[t] += add;
        __syncthreads();
    }
    offs[i] = s[t] - v;
    if (t == 1023) bsum[blockIdx.x] = s[1023];
}

// level-2 scan: exclusive scan of the 256 block sums
__global__ __launch_bounds__(256)
void k_scan2(const int* __restrict__ bsum, int* __restrict__ bbase)
{
    __shared__ int s[256];
    const int t = threadIdx.x;
    const int v = bsum[t];
    s[t] = v;
    __syncthreads();
    for (int d = 1; d < 256; d <<= 1) {
        int add = (t >= d) ? s[t - d] : 0;
        __syncthreads();
        s[t] += add;
        __syncthreads();
    }
    bbase[t] = s[t] - v;
}

// level-3: add block bases; emit offs and cursor
__global__ __launch_bounds__(1024)
void k_scan3(int* __restrict__ offs, const int* __restrict__ bbase, int* __restrict__ cursor)
{
    const int i = blockIdx.x * 1024 + threadIdx.x;
    const int o = offs[i] + bbase[blockIdx.x];
    offs[i] = o;
    cursor[i] = o;
    if (i == 0) offs[NB] = TTOT;
}

__global__ __launch_bounds__(256)
void k_fill(const int* __restrict__ i0, const int* __restrict__ i1,
            const int* __restrict__ i2, int* cursor, unsigned short* __restrict__ tri16)
{
    const int t = blockIdx.x * 256 + threadIdx.x;
    const int a0 = i0[t];
    const int pos = atomicAdd(&cursor[a0], 1);
    tri16[pos] = (unsigned short)((i1[t] & 255) | ((i2[t] & 255) << 8));
}

// ---------------------------------------------------------------- MFMA MLP (2-way f16 split)
// stage 64x128 f32 tile -> 2 LDS f16 buffers (hi/lo), row stride XS shorts
__device__ __forceinline__ void stage2(const float* __restrict__ src,
                                       unsigned short* Xh, unsigned short* Xl, int tid)
{
#pragma unroll
    for (int it = 0; it < 4; ++it) {
        const int r = (tid >> 4) + it * 16;
        const int c = (tid & 15) * 8;
        const float4 v0 = *(const float4*)(src + (size_t)r * H + c);
        const float4 v1 = *(const float4*)(src + (size_t)r * H + c + 4);
        const float x[8] = {v0.x, v0.y, v0.z, v0.w, v1.x, v1.y, v1.z, v1.w};
        ushort8 vh, vl;
#pragma unroll
        for (int j = 0; j < 8; ++j) {
            unsigned short hh, ll;
            split2(x[j], hh, ll);
            vh[j] = hh; vl[j] = ll;
        }
        *(ushort8*)(Xh + r * XS + c) = vh;
        *(ushort8*)(Xl + r * XS + c) = vl;
    }
}

#define MFMA16F(A, B, C) __builtin_amdgcn_mfma_f32_16x16x32_f16(A, B, C, 0, 0, 0)

// one K=128 GEMM pass with SOFTWARE-PIPELINED B loads: while MFMAing kc, the
// 8 B-fragments of kc+1 are already in flight (register double-buffer, all
// indices compile-time after unroll). Attacks the diagnosed L2-latency stall
// (r14 VGPR=52 => compiler wasn't hoisting).
__device__ __forceinline__ void gemm2(const unsigned short* Xh, const unsigned short* Xl,
                                      const unsigned short* __restrict__ wp,
                                      const int rt, const int cb, const int lane,
                                      f32x4 (&acc)[2][4])
{
    const int arow = lane & 15, akb = (lane >> 4) * 8;
    f16x8 Bh[2][4], Bl[2][4];
#pragma unroll
    for (int j = 0; j < 4; ++j) {
        const unsigned short* bp = wp + (size_t)(cb + j) * 1024 + lane * 8;
        Bh[0][j] = ldf16(bp);
        Bl[0][j] = ldf16(bp + 512);
    }
#pragma unroll
    for (int kc = 0; kc < 4; ++kc) {
        if (kc < 3) {
#pragma unroll
            for (int j = 0; j < 4; ++j) {
                const unsigned short* bp =
                    wp + (size_t)((kc + 1) * 8 + cb + j) * 1024 + lane * 8;
                Bh[(kc + 1) & 1][j] = ldf16(bp);
                Bl[(kc + 1) & 1][j] = ldf16(bp + 512);
            }
        }
        const int kin = kc * 32 + akb;
        f16x8 ah[2], al[2];
#pragma unroll
        for (int s = 0; s < 2; ++s) {
            const int ro = (rt + s * 16 + arow) * XS + kin;
            ah[s] = ldf16(Xh + ro);
            al[s] = ldf16(Xl + ro);
        }
#pragma unroll
        for (int j = 0; j < 4; ++j) {
#pragma unroll
            for (int s = 0; s < 2; ++s) {
                acc[s][j] = MFMA16F(ah[s], Bh[kc & 1][j], acc[s][j]);
                acc[s][j] = MFMA16F(al[s], Bh[kc & 1][j], acc[s][j]);
                acc[s][j] = MFMA16F(ah[s], Bl[kc & 1][j], acc[s][j]);
                acc[s][j] = MFMA16F(al[s], Bl[kc & 1][j], acc[s][j]);
            }
        }
    }
}

// m1/m2 body (grid-parity fused): bid parity selects weight set.
__device__ __forceinline__ void mlp_m12_body(int bid, const float* __restrict__ x1,
    const unsigned short* __restrict__ wa1, const float* __restrict__ ba1,
    const float* __restrict__ gg1, const float* __restrict__ bsh1,
    const unsigned short* __restrict__ wb1, const float* __restrict__ bb1,
    float* __restrict__ out1,
    const unsigned short* __restrict__ wa2, const float* __restrict__ ba2,
    const float* __restrict__ gg2, const float* __restrict__ bsh2,
    const unsigned short* __restrict__ wb2, const float* __restrict__ bb2,
    float* __restrict__ out2,
    unsigned short* Xh, unsigned short* Xl, int tid)
{
    const int lane = tid & 63, wid = tid >> 6;
    const int sel = bid & 1;
    const size_t row0 = (size_t)(bid >> 1) * 64;

    const unsigned short* wa = sel ? wa2 : wa1;
    const unsigned short* wb = sel ? wb2 : wb1;
    const float* ba  = sel ? ba2  : ba1;
    const float* gg  = sel ? gg2  : gg1;
    const float* bsh = sel ? bsh2 : bsh1;
    const float* bb  = sel ? bb2  : bb1;
    float* out = sel ? out2 : out1;

    const int rt = (wid >> 1) * 32;
    const int cb = (wid & 1) * 4;

    f32x4 acc[2][4];
#pragma unroll
    for (int s = 0; s < 2; ++s)
#pragma unroll
        for (int j = 0; j < 4; ++j)
#pragma unroll
            for (int q = 0; q < 4; ++q) acc[s][j][q] = 0.f;

    stage2(x1 + row0 * H, Xh, Xl, tid);
    __syncthreads();
    gemm2(Xh, Xl, wa, rt, cb, lane, acc);
    __syncthreads();

    const float inv_s = rsqrtf(1.0f + 1e-5f);
    const int crow = (lane >> 4) * 4, ccol = lane & 15;
#pragma unroll
    for (int j = 0; j < 4; ++j) {
        const int col = (cb + j) * 16 + ccol;
        const float g  = gg[col] * inv_s;
        const float a_ = ba[col];
        const float b_ = bsh[col];
#pragma unroll
        for (int s = 0; s < 2; ++s)
#pragma unroll
            for (int q = 0; q < 4; ++q) {
                float t = fmaf(acc[s][j][q] + a_, g, b_);
                t = fmaxf(t, 0.f);
                unsigned short hh, ll;
                split2(t, hh, ll);
                const int ro = (rt + s * 16 + crow + q) * XS + col;
                Xh[ro] = hh; Xl[ro] = ll;
                acc[s][j][q] = 0.f;
            }
    }
    __syncthreads();

    gemm2(Xh, Xl, wb, rt, cb, lane, acc);

#pragma unroll
    for (int j = 0; j < 4; ++j) {
        const int col = (cb + j) * 16 + ccol;
        const float bbv = bb[col];
#pragma unroll
        for (int s = 0; s < 2; ++s)
#pragma unroll
            for (int q = 0; q < 4; ++q) {
                const int row = rt + s * 16 + crow + q;
                out[(row0 + row) * H + col] = acc[s][j][q] + bbv;
            }
    }
}

// up body: GEMM1 over concat(x1, x2) K=256 via sequential staging; + x1 residual.
__device__ __forceinline__ void mlp_up_body(int bid, const float* __restrict__ x1,
    const float* __restrict__ x2,
    const unsigned short* __restrict__ wpa, const float* __restrict__ ba,
    const float* __restrict__ gg, const float* __restrict__ bsh,
    const unsigned short* __restrict__ wpb, const float* __restrict__ bb,
    float* __restrict__ out,
    unsigned short* Xh, unsigned short* Xl, int tid)
{
    const int lane = tid & 63, wid = tid >> 6;
    const size_t row0 = (size_t)bid * 64;
    const int rt = (wid >> 1) * 32;
    const int cb = (wid & 1) * 4;

    f32x4 acc[2][4];
#pragma unroll
    for (int s = 0; s < 2; ++s)
#pragma unroll
        for (int j = 0; j < 4; ++j)
#pragma unroll
            for (int q = 0; q < 4; ++q) acc[s][j][q] = 0.f;

    stage2(x1 + row0 * H, Xh, Xl, tid);
    __syncthreads();
    gemm2(Xh, Xl, wpa, rt, cb, lane, acc);
    __syncthreads();
    stage2(x2 + row0 * H, Xh, Xl, tid);
    __syncthreads();
    gemm2(Xh, Xl, wpa + 32 * 1024, rt, cb, lane, acc);
    __syncthreads();

    const float inv_s = rsqrtf(1.0f + 1e-5f);
    const int crow = (lane >> 4) * 4, ccol = lane & 15;
#pragma unroll
    for (int j = 0; j < 4; ++j) {
        const int col = (cb + j) * 16 + ccol;
        const float g  = gg[col] * inv_s;
        const float a_ = ba[col];
        const float b_ = bsh[col];
#pragma unroll
        for (int s = 0; s < 2; ++s)
#pragma unroll
            for (int q = 0; q < 4; ++q) {
                float t = fmaf(acc[s][j][q] + a_, g, b_);
                t = fmaxf(t, 0.f);
                unsigned short hh, ll;
                split2(t, hh, ll);
                const int ro = (rt + s * 16 + crow + q) * XS + col;
                Xh[ro] = hh; Xl[ro] = ll;
                acc[s][j][q] = 0.f;
            }
    }
    __syncthreads();

    gemm2(Xh, Xl, wpb, rt, cb, lane, acc);

#pragma unroll
    for (int j = 0; j < 4; ++j) {
        const int col = (cb + j) * 16 + ccol;
        const float bbv = bb[col];
#pragma unroll
        for (int s = 0; s < 2; ++s)
#pragma unroll
            for (int q = 0; q < 4; ++q) {
                const int row = rt + s * 16 + crow + q;
                float o = acc[s][j][q] + bbv + x1[(row0 + row) * H + col];
                out[(row0 + row) * H + col] = o;
            }
    }
}

__global__ __launch_bounds__(256)
void k_mlp_m12(const float* x1,
               const unsigned short* wa1, const float* ba1, const float* gg1,
               const float* bsh1, const unsigned short* wb1, const float* bb1, float* out1,
               const unsigned short* wa2, const float* ba2, const float* gg2,
               const float* bsh2, const unsigned short* wb2, const float* bb2, float* out2)
{
    __shared__ unsigned short Xh[64 * XS], Xl[64 * XS];   // 34 KiB
    mlp_m12_body(blockIdx.x, x1, wa1, ba1, gg1, bsh1, wb1, bb1, out1,
                 wa2, ba2, gg2, bsh2, wb2, bb2, out2, Xh, Xl, threadIdx.x);
}

__global__ __launch_bounds__(256)
void k_mlp_up(const float* x1, const float* x2,
              const unsigned short* wpa, const float* ba, const float* gg,
              const float* bsh, const unsigned short* wpb, const float* bb, float* out)
{
    __shared__ unsigned short Xh[64 * XS], Xl[64 * XS];   // 34 KiB
    mlp_up_body(blockIdx.x, x1, x2, wpa, ba, gg, bsh, wpb, bb, out,
                Xh, Xl, threadIdx.x);
}

// heterogeneous dispatch: blocks [0,1024) run up(chunk cu); blocks [1024,3072)
// run m12 of an INDEPENDENT chunk (next chunk / next layer).
__global__ __launch_bounds__(256)
void k_fused(const float* ux1, const float* ux2,
             const unsigned short* uwpa, const float* uba, const float* ugg,
             const float* ubsh, const unsigned short* uwpb, const float* ubb, float* uout,
             const float* mx1,
             const unsigned short* mwa1, const float* mba1, const float* mgg1,
             const float* mbsh1, const unsigned short* mwb1, const float* mbb1, float* mout1,
             const unsigned short* mwa2, const float* mba2, const float* mgg2,
             const float* mbsh2, const unsigned short* mwb2, const float* mbb2, float* mout2)
{
    __shared__ unsigned short Xh[64 * XS], Xl[64 * XS];   // 34 KiB
    const int bid = blockIdx.x;
    if (bid < ROWS / 64) {
        mlp_up_body(bid, ux1, ux2, uwpa, uba, ugg, ubsh, uwpb, ubb, uout,
                    Xh, Xl, threadIdx.x);
    } else {
        mlp_m12_body(bid - ROWS / 64, mx1, mwa1, mba1, mgg1, mbsh1, mwb1, mbb1, mout1,
                     mwa2, mba2, mgg2, mbsh2, mwb2, mbb2, mout2, Xh, Xl, threadIdx.x);
    }
}

// prepack W[K][128] f32 -> per-(kc,ct) B-fragment blocks: 64 lanes x 8 f16 x {hi,lo}
__global__ __launch_bounds__(64)
void k_prepack2(const float* __restrict__ W, int lstride,
                unsigned short* __restrict__ outp, int ostride)
{
    const int l = blockIdx.y;
    const float* w = W + (size_t)l * lstride;
    unsigned short* o = outp + (size_t)l * ostride + (size_t)blockIdx.x * 1024;
    const int lane = threadIdx.x;
    const int kbase = (blockIdx.x >> 3) * 32 + (lane >> 4) * 8;
    const int col   = (blockIdx.x & 7) * 16 + (lane & 15);
    ushort8 vh, vl;
#pragma unroll
    for (int j = 0; j < 8; ++j) {
        unsigned short hh, ll;
        split2(w[(size_t)(kbase + j) * H + col], hh, ll);
        vh[j] = hh; vl[j] = ll;
    }
    *(ushort8*)(o + lane * 8)       = vh;
    *(ushort8*)(o + 512 + lane * 8) = vl;
}

// ---------------------------------------------------------------- triple (sorted, atomic-free)
__global__ __launch_bounds__(256)
void k_triple_s(const float* __restrict__ h1, const float* __restrict__ h2,
                const unsigned short* __restrict__ tri16,
                const int* __restrict__ offs,      // pre-offset by chunk row base
                float* __restrict__ aggout)
{
    const int lane = threadIdx.x & 63;
    const int lp   = blockIdx.x * 4 + (threadIdx.x >> 6);   // local row in chunk
    const int start = offs[lp], end = offs[lp + 1];         // global tri16 positions
    const size_t base = (size_t)(lp >> 8) * PPG * H + lane * 2;
    float ax = 0.f, ay = 0.f;
    unsigned us = (start < end) ? tri16[start] : 0u;
    for (int t = start; t < end; ++t) {
        const unsigned usn = (t + 1 < end) ? tri16[t + 1] : 0u;   // prefetch next index
        const float2 a = *(const float2*)&h1[base + (size_t)(us & 255u) * H];
        const float2 b = *(const float2*)&h2[base + (size_t)(us >> 8) * H];
        ax = fmaf(a.x, b.x, ax);
        ay = fmaf(a.y, b.y, ay);
        us = usn;
    }
    float2 r;
    r.x = sqrtf(fmaxf(ax, 0.f) + 1e-12f) - sqrtf(fmaxf(-ax, 0.f) + 1e-12f);
    r.y = sqrtf(fmaxf(ay, 0.f) + 1e-12f) - sqrtf(fmaxf(-ay, 0.f) + 1e-12f);
    *(float2*)&aggout[(size_t)lp * H + lane * 2] = r;
}

// ---------------------------------------------------------------- pooling + decode
__global__ __launch_bounds__(256)
void k_pool(const float* __restrict__ ph, const float* __restrict__ Wd,
            const float* __restrict__ bd, float* __restrict__ out)
{
    const int g = blockIdx.x;
    const int tid = threadIdx.x;
    const int c = tid & 127, half = tid >> 7;
    const size_t base = (size_t)g * PPG * H;
    float s = 0.f;
    for (int r = half * 128; r < half * 128 + 128; ++r)
        s += ph[base + (size_t)r * H + c];
    __shared__ float sother[128];
    __shared__ float red[128];
    if (half) sother[c] = s;
    __syncthreads();
    if (!half) {
        const float tot = s + sother[c];
        float d = 0.f;
#pragma unroll
        for (int i = 0; i < 16; ++i)
            d += ph[base + (size_t)(i * 17) * H + c];
        const float diag = d * (1.f / 16.f);
        const float offv = (tot - d) * (1.f / 240.f);
        red[c] = fmaf(diag, Wd[c], offv * Wd[128 + c]);
    }
    __syncthreads();
    if (tid < 64) {
        float r = red[tid] + red[tid + 64];
#pragma unroll
        for (int off = 32; off; off >>= 1) r += __shfl_down(r, off);
        if (tid == 0) out[g] = r + bd[0];
    }
}

// ---------------------------------------------------------------- launch
extern "C" void kernel_launch(void* const* d_in, const int* in_sizes, int n_in,
                              void* d_out, int out_size, void* d_ws, size_t ws_size,
                              hipStream_t stream)
{
    (void)in_sizes; (void)n_in; (void)out_size;
    // workspace layout (bytes)
    const size_t OFF_PH  = 0;                          // f32 [P*H]      134,217,728
    const size_t OFF_HA  = 134217728;                  // f32 [ROWS*H]    33,554,432
    const size_t OFF_HB  = 167772160;                  // f32 [ROWS*H]    33,554,432
    const size_t OFF_AGG = 201326592;                  // f32 [ROWS*H]    33,554,432
    const size_t OFF_TRI = 234881024;                  // u16 [T]          2,097,152
    const size_t OFF_INT = 236978176;                  // counts/offs/cursor/bsum ~3.2 MB
    const size_t OFF_WP  = 240128000;                  // packed weights   1,376,256
    const size_t NEED    = OFF_WP + 1376256;           // ~241.5 MB (proven OK r7-r17)
    if (ws_size < NEED) return;   // diagnostic guard: absmax=488 signature, no fault

    const float* pair_x = (const float*)d_in[0];
    const float* diag_x = (const float*)d_in[1];
    const float* node_h = (const float*)d_in[2];
    const float* edge_h = (const float*)d_in[3];
    const float* W_pair = (const float*)d_in[4];
    const float* W_diag = (const float*)d_in[5];
    const float* Wd     = (const float*)d_in[6];
    const float* bd     = (const float*)d_in[7];
    const float* mW[3][6];
    for (int p = 0; p < 3; ++p)
        for (int q = 0; q < 6; ++q)
            mW[p][q] = (const float*)d_in[8 + p * 6 + q];
    const int* edge_pos = (const int*)d_in[26];
    const int* diag_pos = (const int*)d_in[27];
    const int* tri_idx  = (const int*)d_in[28];

    char* w = (char*)d_ws;
    float*          ph   = (float*)(w + OFF_PH);
    float*          hA   = (float*)(w + OFF_HA);
    float*          hB   = (float*)(w + OFF_HB);
    float*          aggC = (float*)(w + OFF_AGG);
    unsigned short* tri16 = (unsigned short*)(w + OFF_TRI);
    int*            counts = (int*)(w + OFF_INT);
    int*            offs   = counts + NB;              // NB+8 entries
    int*            cursor = offs + NB + 8;            // NB entries
    int*            bsum   = cursor + NB;              // 256
    int*            bbase  = bsum + 256;               // 256
    unsigned short* wp   = (unsigned short*)(w + OFF_WP);

    // packed-weight slots (shorts): block = 1024; m* = 32 blocks, upa = 64 blocks
    const int WPL = 229376;   // per-layer stride
    // slots: m1a 0, m1b 32768, m2a 65536, m2b 98304, upa 131072, upb 196608

    k_init_pair<<<PTOT / 64, 256, 0, stream>>>(pair_x, W_pair, ph);
    k_edge<<<ETOT / 2, 256, 0, stream>>>(edge_h, edge_pos, ph);
    k_diag<<<NTOT / 64, 256, 0, stream>>>(node_h, diag_x, W_diag, diag_pos, ph);

    k_prepack2<<<dim3(32, 3), 64, 0, stream>>>(mW[0][0], 16384, wp + 0,      WPL);
    k_prepack2<<<dim3(32, 3), 64, 0, stream>>>(mW[0][4], 16384, wp + 32768,  WPL);
    k_prepack2<<<dim3(32, 3), 64, 0, stream>>>(mW[1][0], 16384, wp + 65536,  WPL);
    k_prepack2<<<dim3(32, 3), 64, 0, stream>>>(mW[1][4], 16384, wp + 98304,  WPL);
    k_prepack2<<<dim3(64, 3), 64, 0, stream>>>(mW[2][0], 32768, wp + 131072, WPL);
    k_prepack2<<<dim3(32, 3), 64, 0, stream>>>(mW[2][4], 16384, wp + 196608, WPL);

    k_zero<<<NB / 1024, 1024, 0, stream>>>(counts);
    k_count<<<TTOT / 256, 256, 0, stream>>>(tri_idx, counts);
    k_scan1<<<NB / 1024, 1024, 0, stream>>>(counts, offs, bsum);
    k_scan2<<<1, 256, 0, stream>>>(bsum, bbase);
    k_scan3<<<NB / 1024, 1024, 0, stream>>>(offs, bbase, cursor);
    k_fill<<<TTOT / 256, 256, 0, stream>>>(tri_idx, tri_idx + TTOT, tri_idx + 2 * TTOT,
                                           cursor, tri16);

    // software-pipelined main loop: m12(l,c) -> triple(c) -> [up(l,c) || m12(next)]
    // first m12 standalone (layer 0, chunk 0)
    {
        const unsigned short* wl = wp;
        k_mlp_m12<<<ROWS / 64 * 2, 256, 0, stream>>>(ph,
            wl + 0,      mW[0][1], mW[0][2], mW[0][3], wl + 32768,  mW[0][5], hA,
            wl + 65536,  mW[1][1], mW[1][2], mW[1][3], wl + 98304,  mW[1][5], hB);
    }
    for (int l = 0; l < 3; ++l) {
        const unsigned short* wl = wp + (size_t)l * WPL;
        for (int c = 0; c < NCHUNK; ++c) {
            float* phc = ph + (size_t)c * ROWS * H;
            k_triple_s<<<ROWS / 4, 256, 0, stream>>>(hA, hB, tri16,
                                                     offs + (size_t)c * ROWS, aggC);
            const bool has_next = (c < NCHUNK - 1) || (l < 2);
            if (has_next) {
                const int nl = (c < NCHUNK - 1) ? l : l + 1;
                const int nc = (c < NCHUNK - 1) ? c + 1 : 0;
                const unsigned short* wn = wp + (size_t)nl * WPL;
                float* phn = ph + (size_t)nc * ROWS * H;
                k_fused<<<ROWS / 64 * 3, 256, 0, stream>>>(
                    // up(l, c)
                    phc, aggC,
                    wl + 131072, mW[2][1] + l * 128, mW[2][2] + l * 128,
                    mW[2][3] + l * 128, wl + 196608, mW[2][5] + l * 128, phc,
                    // m12(nl, nc)
                    phn,
                    wn + 0,      mW[0][1] + nl * 128, mW[0][2] + nl * 128,
                    mW[0][3] + nl * 128, wn + 32768,  mW[0][5] + nl * 128, hA,
                    wn + 65536,  mW[1][1] + nl * 128, mW[1][2] + nl * 128,
                    mW[1][3] + nl * 128, wn + 98304,  mW[1][5] + nl * 128, hB);
            } else {
                k_mlp_up<<<ROWS / 64, 256, 0, stream>>>(phc, aggC,
                    wl + 131072, mW[2][1] + l * 128, mW[2][2] + l * 128,
                    mW[2][3] + l * 128, wl + 196608, mW[2][5] + l * 128, phc);
            }
        }
    }
    k_pool<<<GNUM, 256, 0, stream>>>(ph, Wd, bd, (float*)d_out);
}

// Round 19
// 1570.595 us; speedup vs baseline: 1.4070x; 1.0826x over previous
//
#include <hip/hip_runtime.h>
#include <hip/hip_bf16.h>

#define H 128
#define POLY 16
#define PPG 256          // pairs per graph
#define GNUM 1024
#define PTOT 262144
#define NTOT 16384
#define ETOT 131072
#define TTOT 1048576

#define NCHUNK 4
#define GPC (GNUM / NCHUNK)        // graphs per chunk = 256
#define ROWS (PTOT / NCHUNK)       // pair rows per chunk = 65536

#define NB PTOT                    // one bucket per output pair row

#define XS 136                     // LDS row stride in shorts (b128 granule-even)
#define TR 32                      // MLP tile rows (17.4 KiB LDS -> 8 blocks/CU)

typedef __attribute__((ext_vector_type(8))) _Float16       f16x8;
typedef __attribute__((ext_vector_type(8))) unsigned short ushort8;
typedef __attribute__((ext_vector_type(4))) float          f32x4;

__device__ __forceinline__ unsigned short f2h(float f) {       // RNE f32 -> f16 bits
    _Float16 h = (_Float16)f;
    return __builtin_bit_cast(unsigned short, h);
}
__device__ __forceinline__ float h2f(unsigned short u) {
    _Float16 h = __builtin_bit_cast(_Float16, u);
    return (float)h;
}
// exact 2-way f16 split: x == hi + lo (f32 24-bit mantissa = 2x f16 12-bit halves)
__device__ __forceinline__ void split2(float x, unsigned short& h, unsigned short& l)
{
    h = f2h(x);
    l = f2h(x - h2f(h));
}
__device__ __forceinline__ f16x8 ldf16(const unsigned short* p)
{
    return __builtin_bit_cast(f16x8, *(const ushort8*)p);
}

// ---------------------------------------------------------------- init
__global__ __launch_bounds__(256)
void k_init_pair(const float* __restrict__ px, const float* __restrict__ Wp,
                 float* __restrict__ ph)
{
    const int tid = threadIdx.x;
    const int c4 = (tid & 31) * 4;
    float4 w[POLY];
#pragma unroll
    for (int k = 0; k < POLY; ++k) w[k] = *(const float4*)(Wp + k * H + c4);
    const size_t r0 = (size_t)blockIdx.x * 64 + (tid >> 5) * 8;
#pragma unroll
    for (int rr = 0; rr < 8; ++rr) {
        const size_t p = r0 + rr;
        const float4* xp = (const float4*)(px + p * POLY);
        const float4 v0 = xp[0], v1 = xp[1], v2 = xp[2], v3 = xp[3];
        const float x[POLY] = {v0.x, v0.y, v0.z, v0.w, v1.x, v1.y, v1.z, v1.w,
                               v2.x, v2.y, v2.z, v2.w, v3.x, v3.y, v3.z, v3.w};
        float4 a = make_float4(0.f, 0.f, 0.f, 0.f);
#pragma unroll
        for (int k = 0; k < POLY; ++k) {
            a.x = fmaf(x[k], w[k].x, a.x);
            a.y = fmaf(x[k], w[k].y, a.y);
            a.z = fmaf(x[k], w[k].z, a.z);
            a.w = fmaf(x[k], w[k].w, a.w);
        }
        *(float4*)(ph + p * H + c4) = a;
    }
}

__global__ __launch_bounds__(256)
void k_edge(const float* __restrict__ eh, const int* __restrict__ epos, float* ph)
{
    const int tid = threadIdx.x;
    const size_t e = (size_t)blockIdx.x * 2 + (tid >> 7);
    const int c = tid & 127;
    atomicAdd(&ph[(size_t)epos[e] * H + c], eh[e * H + c]);
}

__global__ __launch_bounds__(256)
void k_diag(const float* __restrict__ nh, const float* __restrict__ dx,
            const float* __restrict__ Wdg, const int* __restrict__ dpos, float* ph)
{
    const int tid = threadIdx.x;
    const int c4 = (tid & 31) * 4;
    float4 w[POLY];
#pragma unroll
    for (int k = 0; k < POLY; ++k) w[k] = *(const float4*)(Wdg + k * H + c4);
    const size_t n0 = (size_t)blockIdx.x * 64 + (tid >> 5) * 8;
#pragma unroll
    for (int rr = 0; rr < 8; ++rr) {
        const size_t n = n0 + rr;
        const float4* xp = (const float4*)(dx + n * POLY);
        const float4 v0 = xp[0], v1 = xp[1], v2 = xp[2], v3 = xp[3];
        const float x[POLY] = {v0.x, v0.y, v0.z, v0.w, v1.x, v1.y, v1.z, v1.w,
                               v2.x, v2.y, v2.z, v2.w, v3.x, v3.y, v3.z, v3.w};
        const float4 nv = *(const float4*)(nh + n * H + c4);
        float4 a = nv;
#pragma unroll
        for (int k = 0; k < POLY; ++k) {
            a.x = fmaf(x[k], w[k].x, a.x);
            a.y = fmaf(x[k], w[k].y, a.y);
            a.z = fmaf(x[k], w[k].z, a.z);
            a.w = fmaf(x[k], w[k].w, a.w);
        }
        float* dst = ph + (size_t)dpos[n] * H + c4;   // diag_pos unique
        const float4 old = *(const float4*)dst;
        a.x += old.x; a.y += old.y; a.z += old.z; a.w += old.w;
        *(float4*)dst = a;
    }
}

// ---------------------------------------------------------------- triple bucketing (by row)
__global__ __launch_bounds__(1024)
void k_zero(int* counts) { counts[blockIdx.x * 1024 + threadIdx.x] = 0; }

__global__ __launch_bounds__(256)
void k_count(const int* __restrict__ i0, int* counts)
{
    const int t = blockIdx.x * 256 + threadIdx.x;
    atomicAdd(&counts[i0[t]], 1);      // bucket = destination pair row; avg 4/bucket
}

// level-1 scan: 256 blocks x 1024 entries; local exclusive prefix -> offs, block sum -> bsum
__global__ __launch_bounds__(1024)
void k_scan1(const int* __restrict__ counts, int* __restrict__ offs, int* __restrict__ bsum)
{
    __shared__ int s[1024];
    const int t = threadIdx.x;
    const int i = blockIdx.x * 1024 + t;
    const int v = counts[i];
    s[t] = v;
    __syncthreads();
    for (int d = 1; d < 1024; d <<= 1) {
        int add = (t >= d) ? s[t - d] : 0;
        __syncthreads();
        s[t] += add;
        __syncthreads();
    }
    offs[i] = s[t] - v;
    if (t == 1023) bsum[blockIdx.x] = s[1023];
}

// level-2 scan: exclusive scan of the 256 block sums
__global__ __launch_bounds__(256)
void k_scan2(const int* __restrict__ bsum, int* __restrict__ bbase)
{
    __shared__ int s[256];
    const int t = threadIdx.x;
    const int v = bsum[t];
    s[t] = v;
    __syncthreads();
    for (int d = 1; d < 256; d <<= 1) {
        int add = (t >= d) ? s[t - d] : 0;
        __syncthreads();
        s[t] += add;
        __syncthreads();
    }
    bbase[t] = s[t] - v;
}

// level-3: add block bases; emit offs and cursor
__global__ __launch_bounds__(1024)
void k_scan3(int* __restrict__ offs, const int* __restrict__ bbase, int* __restrict__ cursor)
{
    const int i = blockIdx.x * 1024 + threadIdx.x;
    const int o = offs[i] + bbase[blockIdx.x];
    offs[i] = o;
    cursor[i] = o;
    if (i == 0) offs[NB] = TTOT;
}

__global__ __launch_bounds__(256)
void k_fill(const int* __restrict__ i0, const int* __restrict__ i1,
            const int* __restrict__ i2, int* cursor, unsigned short* __restrict__ tri16)
{
    const int t = blockIdx.x * 256 + threadIdx.x;
    const int a0 = i0[t];
    const int pos = atomicAdd(&cursor[a0], 1);
    tri16[pos] = (unsigned short)((i1[t] & 255) | ((i2[t] & 255) << 8));
}

// ---------------------------------------------------------------- MFMA MLP (2-way f16 split)
// stage TR x 128 f32 tile -> 2 LDS f16 buffers (hi/lo), row stride XS shorts
__device__ __forceinline__ void stage2(const float* __restrict__ src,
                                       unsigned short* Xh, unsigned short* Xl, int tid)
{
#pragma unroll
    for (int it = 0; it < TR / 16; ++it) {
        const int r = (tid >> 4) + it * 16;
        const int c = (tid & 15) * 8;
        const float4 v0 = *(const float4*)(src + (size_t)r * H + c);
        const float4 v1 = *(const float4*)(src + (size_t)r * H + c + 4);
        const float x[8] = {v0.x, v0.y, v0.z, v0.w, v1.x, v1.y, v1.z, v1.w};
        ushort8 vh, vl;
#pragma unroll
        for (int j = 0; j < 8; ++j) {
            unsigned short hh, ll;
            split2(x[j], hh, ll);
            vh[j] = hh; vl[j] = ll;
        }
        *(ushort8*)(Xh + r * XS + c) = vh;
        *(ushort8*)(Xl + r * XS + c) = vl;
    }
}

#define MFMA16F(A, B, C) __builtin_amdgcn_mfma_f32_16x16x32_f16(A, B, C, 0, 0, 0)

// one K=128 GEMM pass over the 32-row tile: wave owns ALL 32 rows x its 32 cols
// (cb = wid*2, col-tiles cb..cb+1). Each B-fragment feeds 8 MFMAs (r9 lesson kept).
__device__ __forceinline__ void gemm2(const unsigned short* Xh, const unsigned short* Xl,
                                      const unsigned short* __restrict__ wp,
                                      const int cb, const int lane,
                                      f32x4 (&acc)[2][2])
{
    const int arow = lane & 15, akb = (lane >> 4) * 8;
#pragma unroll
    for (int kc = 0; kc < 4; ++kc) {
        const int kin = kc * 32 + akb;
        f16x8 ah[2], al[2];
#pragma unroll
        for (int s = 0; s < 2; ++s) {
            const int ro = (s * 16 + arow) * XS + kin;
            ah[s] = ldf16(Xh + ro);
            al[s] = ldf16(Xl + ro);
        }
#pragma unroll
        for (int j = 0; j < 2; ++j) {
            const unsigned short* bp = wp + (size_t)(kc * 8 + cb + j) * 1024 + lane * 8;
            const f16x8 bh = ldf16(bp);
            const f16x8 bl = ldf16(bp + 512);
#pragma unroll
            for (int s = 0; s < 2; ++s) {
                acc[s][j] = MFMA16F(ah[s], bh, acc[s][j]);
                acc[s][j] = MFMA16F(al[s], bh, acc[s][j]);
                acc[s][j] = MFMA16F(ah[s], bl, acc[s][j]);
                acc[s][j] = MFMA16F(al[s], bl, acc[s][j]);
            }
        }
    }
}

// m1/m2 body (grid-parity fused): bid parity selects weight set; 32-row tile.
__device__ __forceinline__ void mlp_m12_body(int bid, const float* __restrict__ x1,
    const unsigned short* __restrict__ wa1, const float* __restrict__ ba1,
    const float* __restrict__ gg1, const float* __restrict__ bsh1,
    const unsigned short* __restrict__ wb1, const float* __restrict__ bb1,
    float* __restrict__ out1,
    const unsigned short* __restrict__ wa2, const float* __restrict__ ba2,
    const float* __restrict__ gg2, const float* __restrict__ bsh2,
    const unsigned short* __restrict__ wb2, const float* __restrict__ bb2,
    float* __restrict__ out2,
    unsigned short* Xh, unsigned short* Xl, int tid)
{
    const int lane = tid & 63, wid = tid >> 6;
    const int sel = bid & 1;
    const size_t row0 = (size_t)(bid >> 1) * TR;

    const unsigned short* wa = sel ? wa2 : wa1;
    const unsigned short* wb = sel ? wb2 : wb1;
    const float* ba  = sel ? ba2  : ba1;
    const float* gg  = sel ? gg2  : gg1;
    const float* bsh = sel ? bsh2 : bsh1;
    const float* bb  = sel ? bb2  : bb1;
    float* out = sel ? out2 : out1;

    const int cb = wid * 2;   // wave's 2 col-tiles (32 cols)

    f32x4 acc[2][2];
#pragma unroll
    for (int s = 0; s < 2; ++s)
#pragma unroll
        for (int j = 0; j < 2; ++j)
#pragma unroll
            for (int q = 0; q < 4; ++q) acc[s][j][q] = 0.f;

    stage2(x1 + row0 * H, Xh, Xl, tid);
    __syncthreads();
    gemm2(Xh, Xl, wa, cb, lane, acc);
    __syncthreads();

    const float inv_s = rsqrtf(1.0f + 1e-5f);
    const int crow = (lane >> 4) * 4, ccol = lane & 15;
#pragma unroll
    for (int j = 0; j < 2; ++j) {
        const int col = (cb + j) * 16 + ccol;
        const float g  = gg[col] * inv_s;
        const float a_ = ba[col];
        const float b_ = bsh[col];
#pragma unroll
        for (int s = 0; s < 2; ++s)
#pragma unroll
            for (int q = 0; q < 4; ++q) {
                float t = fmaf(acc[s][j][q] + a_, g, b_);
                t = fmaxf(t, 0.f);
                unsigned short hh, ll;
                split2(t, hh, ll);
                const int ro = (s * 16 + crow + q) * XS + col;
                Xh[ro] = hh; Xl[ro] = ll;
                acc[s][j][q] = 0.f;
            }
    }
    __syncthreads();

    gemm2(Xh, Xl, wb, cb, lane, acc);

#pragma unroll
    for (int j = 0; j < 2; ++j) {
        const int col = (cb + j) * 16 + ccol;
        const float bbv = bb[col];
#pragma unroll
        for (int s = 0; s < 2; ++s)
#pragma unroll
            for (int q = 0; q < 4; ++q) {
                const int row = s * 16 + crow + q;
                out[(row0 + row) * H + col] = acc[s][j][q] + bbv;
            }
    }
}

// up body: GEMM1 over concat(x1, x2) K=256 via sequential staging; + x1 residual.
__device__ __forceinline__ void mlp_up_body(int bid, const float* __restrict__ x1,
    const float* __restrict__ x2,
    const unsigned short* __restrict__ wpa, const float* __restrict__ ba,
    const float* __restrict__ gg, const float* __restrict__ bsh,
    const unsigned short* __restrict__ wpb, const float* __restrict__ bb,
    float* __restrict__ out,
    unsigned short* Xh, unsigned short* Xl, int tid)
{
    const int lane = tid & 63, wid = tid >> 6;
    const size_t row0 = (size_t)bid * TR;
    const int cb = wid * 2;

    f32x4 acc[2][2];
#pragma unroll
    for (int s = 0; s < 2; ++s)
#pragma unroll
        for (int j = 0; j < 2; ++j)
#pragma unroll
            for (int q = 0; q < 4; ++q) acc[s][j][q] = 0.f;

    stage2(x1 + row0 * H, Xh, Xl, tid);
    __syncthreads();
    gemm2(Xh, Xl, wpa, cb, lane, acc);
    __syncthreads();
    stage2(x2 + row0 * H, Xh, Xl, tid);
    __syncthreads();
    gemm2(Xh, Xl, wpa + 32 * 1024, cb, lane, acc);
    __syncthreads();

    const float inv_s = rsqrtf(1.0f + 1e-5f);
    const int crow = (lane >> 4) * 4, ccol = lane & 15;
#pragma unroll
    for (int j = 0; j < 2; ++j) {
        const int col = (cb + j) * 16 + ccol;
        const float g  = gg[col] * inv_s;
        const float a_ = ba[col];
        const float b_ = bsh[col];
#pragma unroll
        for (int s = 0; s < 2; ++s)
#pragma unroll
            for (int q = 0; q < 4; ++q) {
                float t = fmaf(acc[s][j][q] + a_, g, b_);
                t = fmaxf(t, 0.f);
                unsigned short hh, ll;
                split2(t, hh, ll);
                const int ro = (s * 16 + crow + q) * XS + col;
                Xh[ro] = hh; Xl[ro] = ll;
                acc[s][j][q] = 0.f;
            }
    }
    __syncthreads();

    gemm2(Xh, Xl, wpb, cb, lane, acc);

#pragma unroll
    for (int j = 0; j < 2; ++j) {
        const int col = (cb + j) * 16 + ccol;
        const float bbv = bb[col];
#pragma unroll
        for (int s = 0; s < 2; ++s)
#pragma unroll
            for (int q = 0; q < 4; ++q) {
                const int row = s * 16 + crow + q;
                float o = acc[s][j][q] + bbv + x1[(row0 + row) * H + col];
                out[(row0 + row) * H + col] = o;
            }
    }
}

__global__ __launch_bounds__(256)
void k_mlp_m12(const float* x1,
               const unsigned short* wa1, const float* ba1, const float* gg1,
               const float* bsh1, const unsigned short* wb1, const float* bb1, float* out1,
               const unsigned short* wa2, const float* ba2, const float* gg2,
               const float* bsh2, const unsigned short* wb2, const float* bb2, float* out2)
{
    __shared__ unsigned short Xh[TR * XS], Xl[TR * XS];   // 17.4 KiB
    mlp_m12_body(blockIdx.x, x1, wa1, ba1, gg1, bsh1, wb1, bb1, out1,
                 wa2, ba2, gg2, bsh2, wb2, bb2, out2, Xh, Xl, threadIdx.x);
}

__global__ __launch_bounds__(256)
void k_mlp_up(const float* x1, const float* x2,
              const unsigned short* wpa, const float* ba, const float* gg,
              const float* bsh, const unsigned short* wpb, const float* bb, float* out)
{
    __shared__ unsigned short Xh[TR * XS], Xl[TR * XS];   // 17.4 KiB
    mlp_up_body(blockIdx.x, x1, x2, wpa, ba, gg, bsh, wpb, bb, out,
                Xh, Xl, threadIdx.x);
}

// heterogeneous dispatch: blocks [0, ROWS/TR) run up(chunk cu); rest run m12
// of an INDEPENDENT chunk (next chunk / next layer).
__global__ __launch_bounds__(256)
void k_fused(const float* ux1, const float* ux2,
             const unsigned short* uwpa, const float* uba, const float* ugg,
             const float* ubsh, const unsigned short* uwpb, const float* ubb, float* uout,
             const float* mx1,
             const unsigned short* mwa1, const float* mba1, const float* mgg1,
             const float* mbsh1, const unsigned short* mwb1, const float* mbb1, float* mout1,
             const unsigned short* mwa2, const float* mba2, const float* mgg2,
             const float* mbsh2, const unsigned short* mwb2, const float* mbb2, float* mout2)
{
    __shared__ unsigned short Xh[TR * XS], Xl[TR * XS];   // 17.4 KiB
    const int bid = blockIdx.x;
    if (bid < ROWS / TR) {
        mlp_up_body(bid, ux1, ux2, uwpa, uba, ugg, ubsh, uwpb, ubb, uout,
                    Xh, Xl, threadIdx.x);
    } else {
        mlp_m12_body(bid - ROWS / TR, mx1, mwa1, mba1, mgg1, mbsh1, mwb1, mbb1, mout1,
                     mwa2, mba2, mgg2, mbsh2, mwb2, mbb2, mout2, Xh, Xl, threadIdx.x);
    }
}

// prepack W[K][128] f32 -> per-(kc,ct) B-fragment blocks: 64 lanes x 8 f16 x {hi,lo}
__global__ __launch_bounds__(64)
void k_prepack2(const float* __restrict__ W, int lstride,
                unsigned short* __restrict__ outp, int ostride)
{
    const int l = blockIdx.y;
    const float* w = W + (size_t)l * lstride;
    unsigned short* o = outp + (size_t)l * ostride + (size_t)blockIdx.x * 1024;
    const int lane = threadIdx.x;
    const int kbase = (blockIdx.x >> 3) * 32 + (lane >> 4) * 8;
    const int col   = (blockIdx.x & 7) * 16 + (lane & 15);
    ushort8 vh, vl;
#pragma unroll
    for (int j = 0; j < 8; ++j) {
        unsigned short hh, ll;
        split2(w[(size_t)(kbase + j) * H + col], hh, ll);
        vh[j] = hh; vl[j] = ll;
    }
    *(ushort8*)(o + lane * 8)       = vh;
    *(ushort8*)(o + 512 + lane * 8) = vl;
}

// ---------------------------------------------------------------- triple (sorted, atomic-free)
__global__ __launch_bounds__(256)
void k_triple_s(const float* __restrict__ h1, const float* __restrict__ h2,
                const unsigned short* __restrict__ tri16,
                const int* __restrict__ offs,      // pre-offset by chunk row base
                float* __restrict__ aggout)
{
    const int lane = threadIdx.x & 63;
    const int lp   = blockIdx.x * 4 + (threadIdx.x >> 6);   // local row in chunk
    const int start = offs[lp], end = offs[lp + 1];         // global tri16 positions
    const size_t base = (size_t)(lp >> 8) * PPG * H + lane * 2;
    float ax = 0.f, ay = 0.f;
    unsigned us = (start < end) ? tri16[start] : 0u;
    for (int t = start; t < end; ++t) {
        const unsigned usn = (t + 1 < end) ? tri16[t + 1] : 0u;   // prefetch next index
        const float2 a = *(const float2*)&h1[base + (size_t)(us & 255u) * H];
        const float2 b = *(const float2*)&h2[base + (size_t)(us >> 8) * H];
        ax = fmaf(a.x, b.x, ax);
        ay = fmaf(a.y, b.y, ay);
        us = usn;
    }
    float2 r;
    r.x = sqrtf(fmaxf(ax, 0.f) + 1e-12f) - sqrtf(fmaxf(-ax, 0.f) + 1e-12f);
    r.y = sqrtf(fmaxf(ay, 0.f) + 1e-12f) - sqrtf(fmaxf(-ay, 0.f) + 1e-12f);
    *(float2*)&aggout[(size_t)lp * H + lane * 2] = r;
}

// ---------------------------------------------------------------- pooling + decode
__global__ __launch_bounds__(256)
void k_pool(const float* __restrict__ ph, const float* __restrict__ Wd,
            const float* __restrict__ bd, float* __restrict__ out)
{
    const int g = blockIdx.x;
    const int tid = threadIdx.x;
    const int c = tid & 127, half = tid >> 7;
    const size_t base = (size_t)g * PPG * H;
    float s = 0.f;
    for (int r = half * 128; r < half * 128 + 128; ++r)
        s += ph[base + (size_t)r * H + c];
    __shared__ float sother[128];
    __shared__ float red[128];
    if (half) sother[c] = s;
    __syncthreads();
    if (!half) {
        const float tot = s + sother[c];
        float d = 0.f;
#pragma unroll
        for (int i = 0; i < 16; ++i)
            d += ph[base + (size_t)(i * 17) * H + c];
        const float diag = d * (1.f / 16.f);
        const float offv = (tot - d) * (1.f / 240.f);
        red[c] = fmaf(diag, Wd[c], offv * Wd[128 + c]);
    }
    __syncthreads();
    if (tid < 64) {
        float r = red[tid] + red[tid + 64];
#pragma unroll
        for (int off = 32; off; off >>= 1) r += __shfl_down(r, off);
        if (tid == 0) out[g] = r + bd[0];
    }
}

// ---------------------------------------------------------------- launch
extern "C" void kernel_launch(void* const* d_in, const int* in_sizes, int n_in,
                              void* d_out, int out_size, void* d_ws, size_t ws_size,
                              hipStream_t stream)
{
    (void)in_sizes; (void)n_in; (void)out_size;
    // workspace layout (bytes)
    const size_t OFF_PH  = 0;                          // f32 [P*H]      134,217,728
    const size_t OFF_HA  = 134217728;                  // f32 [ROWS*H]    33,554,432
    const size_t OFF_HB  = 167772160;                  // f32 [ROWS*H]    33,554,432
    const size_t OFF_AGG = 201326592;                  // f32 [ROWS*H]    33,554,432
    const size_t OFF_TRI = 234881024;                  // u16 [T]          2,097,152
    const size_t OFF_INT = 236978176;                  // counts/offs/cursor/bsum ~3.2 MB
    const size_t OFF_WP  = 240128000;                  // packed weights   1,376,256
    const size_t NEED    = OFF_WP + 1376256;           // ~241.5 MB (proven OK r7-r18)
    if (ws_size < NEED) return;   // diagnostic guard: absmax=488 signature, no fault

    const float* pair_x = (const float*)d_in[0];
    const float* diag_x = (const float*)d_in[1];
    const float* node_h = (const float*)d_in[2];
    const float* edge_h = (const float*)d_in[3];
    const float* W_pair = (const float*)d_in[4];
    const float* W_diag = (const float*)d_in[5];
    const float* Wd     = (const float*)d_in[6];
    const float* bd     = (const float*)d_in[7];
    const float* mW[3][6];
    for (int p = 0; p < 3; ++p)
        for (int q = 0; q < 6; ++q)
            mW[p][q] = (const float*)d_in[8 + p * 6 + q];
    const int* edge_pos = (const int*)d_in[26];
    const int* diag_pos = (const int*)d_in[27];
    const int* tri_idx  = (const int*)d_in[28];

    char* w = (char*)d_ws;
    float*          ph   = (float*)(w + OFF_PH);
    float*          hA   = (float*)(w + OFF_HA);
    float*          hB   = (float*)(w + OFF_HB);
    float*          aggC = (float*)(w + OFF_AGG);
    unsigned short* tri16 = (unsigned short*)(w + OFF_TRI);
    int*            counts = (int*)(w + OFF_INT);
    int*            offs   = counts + NB;              // NB+8 entries
    int*            cursor = offs + NB + 8;            // NB entries
    int*            bsum   = cursor + NB;              // 256
    int*            bbase  = bsum + 256;               // 256
    unsigned short* wp   = (unsigned short*)(w + OFF_WP);

    // packed-weight slots (shorts): block = 1024; m* = 32 blocks, upa = 64 blocks
    const int WPL = 229376;   // per-layer stride
    // slots: m1a 0, m1b 32768, m2a 65536, m2b 98304, upa 131072, upb 196608

    k_init_pair<<<PTOT / 64, 256, 0, stream>>>(pair_x, W_pair, ph);
    k_edge<<<ETOT / 2, 256, 0, stream>>>(edge_h, edge_pos, ph);
    k_diag<<<NTOT / 64, 256, 0, stream>>>(node_h, diag_x, W_diag, diag_pos, ph);

    k_prepack2<<<dim3(32, 3), 64, 0, stream>>>(mW[0][0], 16384, wp + 0,      WPL);
    k_prepack2<<<dim3(32, 3), 64, 0, stream>>>(mW[0][4], 16384, wp + 32768,  WPL);
    k_prepack2<<<dim3(32, 3), 64, 0, stream>>>(mW[1][0], 16384, wp + 65536,  WPL);
    k_prepack2<<<dim3(32, 3), 64, 0, stream>>>(mW[1][4], 16384, wp + 98304,  WPL);
    k_prepack2<<<dim3(64, 3), 64, 0, stream>>>(mW[2][0], 32768, wp + 131072, WPL);
    k_prepack2<<<dim3(32, 3), 64, 0, stream>>>(mW[2][4], 16384, wp + 196608, WPL);

    k_zero<<<NB / 1024, 1024, 0, stream>>>(counts);
    k_count<<<TTOT / 256, 256, 0, stream>>>(tri_idx, counts);
    k_scan1<<<NB / 1024, 1024, 0, stream>>>(counts, offs, bsum);
    k_scan2<<<1, 256, 0, stream>>>(bsum, bbase);
    k_scan3<<<NB / 1024, 1024, 0, stream>>>(offs, bbase, cursor);
    k_fill<<<TTOT / 256, 256, 0, stream>>>(tri_idx, tri_idx + TTOT, tri_idx + 2 * TTOT,
                                           cursor, tri16);

    // software-pipelined main loop: m12(l,c) -> triple(c) -> [up(l,c) || m12(next)]
    // first m12 standalone (layer 0, chunk 0)
    {
        const unsigned short* wl = wp;
        k_mlp_m12<<<ROWS / TR * 2, 256, 0, stream>>>(ph,
            wl + 0,      mW[0][1], mW[0][2], mW[0][3], wl + 32768,  mW[0][5], hA,
            wl + 65536,  mW[1][1], mW[1][2], mW[1][3], wl + 98304,  mW[1][5], hB);
    }
    for (int l = 0; l < 3; ++l) {
        const unsigned short* wl = wp + (size_t)l * WPL;
        for (int c = 0; c < NCHUNK; ++c) {
            float* phc = ph + (size_t)c * ROWS * H;
            k_triple_s<<<ROWS / 4, 256, 0, stream>>>(hA, hB, tri16,
                                                     offs + (size_t)c * ROWS, aggC);
            const bool has_next = (c < NCHUNK - 1) || (l < 2);
            if (has_next) {
                const int nl = (c < NCHUNK - 1) ? l : l + 1;
                const int nc = (c < NCHUNK - 1) ? c + 1 : 0;
                const unsigned short* wn = wp + (size_t)nl * WPL;
                float* phn = ph + (size_t)nc * ROWS * H;
                k_fused<<<ROWS / TR * 3, 256, 0, stream>>>(
                    // up(l, c)
                    phc, aggC,
                    wl + 131072, mW[2][1] + l * 128, mW[2][2] + l * 128,
                    mW[2][3] + l * 128, wl + 196608, mW[2][5] + l * 128, phc,
                    // m12(nl, nc)
                    phn,
                    wn + 0,      mW[0][1] + nl * 128, mW[0][2] + nl * 128,
                    mW[0][3] + nl * 128, wn + 32768,  mW[0][5] + nl * 128, hA,
                    wn + 65536,  mW[1][1] + nl * 128, mW[1][2] + nl * 128,
                    mW[1][3] + nl * 128, wn + 98304,  mW[1][5] + nl * 128, hB);
            } else {
                k_mlp_up<<<ROWS / TR, 256, 0, stream>>>(phc, aggC,
                    wl + 131072, mW[2][1] + l * 128, mW[2][2] + l * 128,
                    mW[2][3] + l * 128, wl + 196608, mW[2][5] + l * 128, phc);
            }
        }
    }
    k_pool<<<GNUM, 256, 0, stream>>>(ph, Wd, bd, (float*)d_out);
}